// Round 4
// baseline (349.342 us; speedup 1.0000x reference)
//
#include <hip/hip_runtime.h>
#include <stdint.h>

// ---------------- problem dims ----------------
#define B_DIM 64
#define P_DIM 225
#define K_DIM 16
#define D_DIM 640
#define M_REAL (B_DIM * P_DIM)   // 14400 query rows
#define N_REAL (K_DIM * P_DIM)   // 3600 reference rows

// ---------------- GEMM tiling ----------------
#define BM 128
#define BN 128
#define BKT 32
#define MTILES 113               // ceil(14400/128) -> Mpad 14464
#define NTILES 29                // ceil(3600/128)  -> Npad 3712
#define MPAD (MTILES * BM)
#define NPAD (NTILES * BN)
#define MCHUNK 15                // ceil(MTILES/8) per-XCD bm groups

typedef __bf16 bf16x8 __attribute__((ext_vector_type(8)));
typedef float f32x4 __attribute__((ext_vector_type(4)));

// ---------------- helpers ----------------
__device__ __forceinline__ unsigned short f2bf(float f) {
  union { float f; unsigned u; } v; v.f = f;
  unsigned u = v.u;
  return (unsigned short)((u + 0x7FFFu + ((u >> 16) & 1u)) >> 16);  // RNE
}

// monotone float -> uint key (order-preserving), for atomicMax on floats
__device__ __forceinline__ unsigned f2key(float f) {
  union { float f; unsigned u; } v; v.f = f;
  unsigned u = v.u;
  return (u & 0x80000000u) ? ~u : (u | 0x80000000u);
}
__device__ __forceinline__ float key2f(unsigned k) {
  unsigned b = (k & 0x80000000u) ? (k ^ 0x80000000u) : ~k;
  union { unsigned u; float f; } v; v.u = b;
  return v.f;
}

__device__ __forceinline__ void gl_lds16(const void* g, void* l) {
  __builtin_amdgcn_global_load_lds(
      (const __attribute__((address_space(1))) void*)g,
      (__attribute__((address_space(3))) void*)l,
      16, 0, 0);
}

// =====================================================================
// Kernel A:
//   blocks [0,16)                : adapter stage 1 (first so they start
//                                  at t=0 and hide under staging blocks)
//                                  h1[k][j] = relu(r_img[k] . w1[:,j])
//   blocks [16, 16+QBLKS)        : q rows, 4 per block (+rowmax zero)
//   blocks [16+QBLKS, ...+RBLKS) : r rows, 4 per block
// =====================================================================
#define QBLKS (MPAD / 4)
#define RBLKS (NPAD / 4)
#define ABLKS 16
__global__ __launch_bounds__(256) void stage_all_kernel(
    const float* __restrict__ q, const float* __restrict__ r,
    const float* __restrict__ r_img, const float* __restrict__ aw1,
    unsigned short* __restrict__ qb, unsigned short* __restrict__ rb,
    float* __restrict__ qinv, unsigned* __restrict__ rowmax,
    float* __restrict__ h1) {
  const int blk = blockIdx.x;
  const int tid = threadIdx.x;

  if (blk < ABLKS) {
    // ---- adapter stage 1: one block per k, thread j owns one column ----
    __shared__ float rk_s[D_DIM];
    const int k = blk;
    for (int i = tid; i < D_DIM; i += 256) rk_s[i] = r_img[k * D_DIM + i];
    __syncthreads();
    if (tid < 160) {
      const int j = tid;
      float a = 0.f;
#pragma unroll 8
      for (int d = 0; d < D_DIM; d++) a += rk_s[d] * aw1[d * 160 + j];
      h1[k * 160 + j] = fmaxf(a, 0.f);
    }
    return;
  }

  if (blk < ABLKS + QBLKS) {
    int row = (blk - ABLKS) * 4 + (tid >> 6);
    int lane = tid & 63;
    if (lane == 0) rowmax[row] = 0u;  // key-space minimum
    unsigned short* dst = qb + (long)row * D_DIM;
    if (row >= M_REAL) {
#pragma unroll
      for (int i = 0; i < 10; i++) dst[i * 64 + lane] = 0;
      return;
    }
    const float* src = q + (long)row * D_DIM;
    float v[10];
    float ss = 0.f;
#pragma unroll
    for (int i = 0; i < 10; i++) { v[i] = src[i * 64 + lane]; ss += v[i] * v[i]; }
#pragma unroll
    for (int off = 32; off > 0; off >>= 1) ss += __shfl_xor(ss, off);
    float inv = 1.f / (sqrtf(ss) + 1e-6f);
    if (lane == 0) qinv[row] = inv;
#pragma unroll
    for (int i = 0; i < 10; i++) dst[i * 64 + lane] = f2bf(v[i]);
    return;
  }

  {
    int row = (blk - ABLKS - QBLKS) * 4 + (tid >> 6);
    int lane = tid & 63;
    unsigned short* dst = rb + (long)row * D_DIM;
    if (row >= N_REAL) {
#pragma unroll
      for (int i = 0; i < 10; i++) dst[i * 64 + lane] = 0;
      return;
    }
    const float* src = r + (long)row * D_DIM;
    float v[10];
    float ss = 0.f;
#pragma unroll
    for (int i = 0; i < 10; i++) { v[i] = src[i * 64 + lane]; ss += v[i] * v[i]; }
#pragma unroll
    for (int off = 32; off > 0; off >>= 1) ss += __shfl_xor(ss, off);
    float sc = 1.f / (sqrtf(ss) + 1e-6f);
#pragma unroll
    for (int i = 0; i < 10; i++) dst[i * 64 + lane] = f2bf(v[i] * sc);
  }
}

// =====================================================================
// Kernel B: fused bf16 MFMA GEMM + row-max, XCD-ownership swizzle
// =====================================================================
__global__ __launch_bounds__(256) void sim_max_kernel(
    const unsigned short* __restrict__ Qb,
    const unsigned short* __restrict__ Rb,
    unsigned* __restrict__ rowmax) {
  __shared__ __attribute__((aligned(16))) unsigned short As[BM * BKT];  // 8 KB
  __shared__ __attribute__((aligned(16))) unsigned short Bs[BN * BKT];  // 8 KB

  // XCD-ownership swizzle: xcd owns bm = {xcd, xcd+8, ...}, bn fastest.
  const int xcd = blockIdx.x & 7;
  const int idx = blockIdx.x >> 3;
  const int bm = xcd + 8 * (idx / NTILES);
  const int bn = idx % NTILES;
  if (bm >= MTILES) return;

  const int tid = threadIdx.x;
  const int wave = tid >> 6, lane = tid & 63;
  const int wr = wave >> 1, wc = wave & 1;
  const int q = lane >> 4, m0 = lane & 15;

  // staging geometry: chunk c of wave -> LDS bytes [((wave*2+c)*64+lane)*16, +16)
  const int fA0 = ((wave * 2 + 0) * 64 + lane) * 16;
  const int fA1 = ((wave * 2 + 1) * 64 + lane) * 16;
  const int rowA0 = fA0 >> 6, colA0 = (fA0 & 63) >> 1;  // row stride 32 bf16 = 64 B
  const int rowA1 = fA1 >> 6, colA1 = (fA1 & 63) >> 1;

  const int aBase = bm * BM;
  const int bBase = bn * BN;

  f32x4 zero = {0.f, 0.f, 0.f, 0.f};
  f32x4 acc[4][4];
#pragma unroll
  for (int i = 0; i < 4; i++)
#pragma unroll
    for (int j = 0; j < 4; j++) acc[i][j] = zero;

  for (int k0 = 0; k0 < D_DIM; k0 += BKT) {
    gl_lds16(Qb + (aBase + rowA0) * D_DIM + k0 + colA0, &As[fA0 / 2]);
    gl_lds16(Qb + (aBase + rowA1) * D_DIM + k0 + colA1, &As[fA1 / 2]);
    gl_lds16(Rb + (bBase + rowA0) * D_DIM + k0 + colA0, &Bs[fA0 / 2]);
    gl_lds16(Rb + (bBase + rowA1) * D_DIM + k0 + colA1, &Bs[fA1 / 2]);
    __syncthreads();  // drains vmcnt -> LDS tiles ready

    bf16x8 af[4], bfr[4];
#pragma unroll
    for (int mi = 0; mi < 4; mi++)
      af[mi] = *(const bf16x8*)&As[(wr * 64 + mi * 16 + m0) * BKT + q * 8];
#pragma unroll
    for (int ni = 0; ni < 4; ni++)
      bfr[ni] = *(const bf16x8*)&Bs[(wc * 64 + ni * 16 + m0) * BKT + q * 8];
#pragma unroll
    for (int mi = 0; mi < 4; mi++)
#pragma unroll
      for (int ni = 0; ni < 4; ni++)
        acc[mi][ni] = __builtin_amdgcn_mfma_f32_16x16x32_bf16(
            af[mi], bfr[ni], acc[mi][ni], 0, 0, 0);
    __syncthreads();  // protect LDS before next-iter overwrite
  }

  // epilogue: per-row max over this block's 128 columns, then global atomicMax
  const int colBase = bn * BN + wc * 64;
#pragma unroll
  for (int mi = 0; mi < 4; mi++) {
    float rmax[4] = {-3.0e38f, -3.0e38f, -3.0e38f, -3.0e38f};
#pragma unroll
    for (int ni = 0; ni < 4; ni++) {
      bool valid = (colBase + ni * 16 + m0) < N_REAL;
#pragma unroll
      for (int r = 0; r < 4; r++) {
        float v = valid ? acc[mi][ni][r] : -3.0e38f;
        rmax[r] = fmaxf(rmax[r], v);
      }
    }
#pragma unroll
    for (int r = 0; r < 4; r++) {
      float v = rmax[r];
      v = fmaxf(v, __shfl_xor(v, 1));
      v = fmaxf(v, __shfl_xor(v, 2));
      v = fmaxf(v, __shfl_xor(v, 4));
      v = fmaxf(v, __shfl_xor(v, 8));
      rmax[r] = v;
    }
    if (m0 == 0) {
      int row = bm * BM + wr * 64 + mi * 16 + q * 4;
#pragma unroll
      for (int r = 0; r < 4; r++)
        atomicMax(&rowmax[row + r], f2key(rmax[r]));
    }
  }
}

// =====================================================================
// Kernel C: finale — per batch element b:
//   amap + amean + s_map head + (favg from h1, redundant per block) +
//   s_ref head + final score. 64 blocks x 256.
// =====================================================================
__global__ __launch_bounds__(256) void finale_kernel(
    const unsigned* __restrict__ rowmax, const float* __restrict__ qinv,
    const float* __restrict__ q_img, const float* __restrict__ h1,
    const float* __restrict__ aw2,
    const float* __restrict__ hw1, const float* __restrict__ hb1,
    const float* __restrict__ hg2, const float* __restrict__ hbe2,
    const float* __restrict__ hw2, const float* __restrict__ hb2,
    const float* __restrict__ hg3, const float* __restrict__ hbe3,
    const float* __restrict__ hw3, const float* __restrict__ hb3,
    const float* __restrict__ rw1, const float* __restrict__ rb1,
    const float* __restrict__ rg2, const float* __restrict__ rbe2,
    const float* __restrict__ rw2, const float* __restrict__ rb2,
    const float* __restrict__ rg3, const float* __restrict__ rbe3,
    const float* __restrict__ rw3, const float* __restrict__ rb3,
    float* __restrict__ out) {
  int b = blockIdx.x, t = threadIdx.x;
  __shared__ float h1a[16 * 160];   // adapter hidden (10 KB)
  __shared__ float amap[P_DIM];
  __shared__ float red[256];
  __shared__ float x[D_DIM];
  __shared__ float h1s[128];
  __shared__ float h2s[64];
  __shared__ float smap_s;

  // load adapter hidden into LDS
#pragma unroll
  for (int i = 0; i < 10; i++) h1a[i * 256 + t] = h1[i * 256 + t];

  // amap
  float av = 0.f;
  if (t < P_DIM) {
    int row = b * P_DIM + t;
    float mx = key2f(rowmax[row]);
    av = 0.5f * (1.f - mx * qinv[row]);
    amap[t] = av;
  }
  red[t] = av;
  __syncthreads();
  for (int s = 128; s > 0; s >>= 1) {
    if (t < s) red[t] += red[t + s];
    __syncthreads();
  }
  float amean = red[0] * (1.f / 225.f);  // uniform after reduction

  // ---- s_map head (input amap, 225) ----
  if (t < 128) {
    float a0 = hb1[t], a1 = 0.f, a2 = 0.f;
#pragma unroll 5
    for (int p = 0; p < P_DIM; p += 3) {  // 225 = 75*3
      a0 += amap[p + 0] * hw1[(p + 0) * 128 + t];
      a1 += amap[p + 1] * hw1[(p + 1) * 128 + t];
      a2 += amap[p + 2] * hw1[(p + 2) * 128 + t];
    }
    float a = a0 + a1 + a2;
    h1s[t] = fmaxf(a, 0.f) * hg2[t] + hbe2[t];
  }
  __syncthreads();
  if (t < 64) {
    float a = hb2[t];
#pragma unroll 8
    for (int j = 0; j < 128; j++) a += h1s[j] * hw2[j * 64 + t];
    h2s[t] = fmaxf(a, 0.f) * hg3[t] + hbe3[t];
  }
  __syncthreads();
  if (t < 64) {
    float p = h2s[t] * hw3[t];
    p += __shfl_xor(p, 32); p += __shfl_xor(p, 16); p += __shfl_xor(p, 8);
    p += __shfl_xor(p, 4);  p += __shfl_xor(p, 2);  p += __shfl_xor(p, 1);
    if (t == 0) smap_s = 1.f / (1.f + expf(-(p + hb3[0])));
  }
  __syncthreads();

  // ---- adapter stage 2 (redundant per block): x[d] = q_img[b][d] - favg[d]
  for (int d = t; d < D_DIM; d += 256) {
    float a[K_DIM];
#pragma unroll
    for (int k = 0; k < K_DIM; k++) a[k] = 0.f;
#pragma unroll 4
    for (int j = 0; j < 160; j++) {
      float w = aw2[j * D_DIM + d];
#pragma unroll
      for (int k = 0; k < K_DIM; k++) a[k] += h1a[k * 160 + j] * w;
    }
    float s = 0.f;
#pragma unroll
    for (int k = 0; k < K_DIM; k++) s += fmaxf(a[k], 0.f);
    x[d] = q_img[b * D_DIM + d] - s * (1.f / 16.f);
  }
  __syncthreads();

  // ---- s_ref head (input x, 640) ----
  if (t < 128) {
    float a0 = rb1[t], a1 = 0.f, a2 = 0.f, a3 = 0.f;
#pragma unroll 4
    for (int d = 0; d < D_DIM; d += 4) {
      a0 += x[d + 0] * rw1[(d + 0) * 128 + t];
      a1 += x[d + 1] * rw1[(d + 1) * 128 + t];
      a2 += x[d + 2] * rw1[(d + 2) * 128 + t];
      a3 += x[d + 3] * rw1[(d + 3) * 128 + t];
    }
    float a = a0 + a1 + a2 + a3;
    h1s[t] = fmaxf(a, 0.f) * rg2[t] + rbe2[t];
  }
  __syncthreads();
  if (t < 64) {
    float a = rb2[t];
#pragma unroll 8
    for (int j = 0; j < 128; j++) a += h1s[j] * rw2[j * 64 + t];
    h2s[t] = fmaxf(a, 0.f) * rg3[t] + rbe3[t];
  }
  __syncthreads();
  if (t < 64) {
    float p = h2s[t] * rw3[t];
    p += __shfl_xor(p, 32); p += __shfl_xor(p, 16); p += __shfl_xor(p, 8);
    p += __shfl_xor(p, 4);  p += __shfl_xor(p, 2);  p += __shfl_xor(p, 1);
    if (t == 0) {
      float sref = 1.f / (1.f + expf(-(p + rb3[0])));
      out[b] = 0.5f * (sref + smap_s) + amean;
    }
  }
}

// ---------------- launch ----------------
extern "C" void kernel_launch(void* const* d_in, const int* in_sizes, int n_in,
                              void* d_out, int out_size, void* d_ws, size_t ws_size,
                              hipStream_t stream) {
  const float* q_patch = (const float*)d_in[0];
  const float* r_patch = (const float*)d_in[1];
  const float* q_img   = (const float*)d_in[2];
  const float* r_img   = (const float*)d_in[3];
  const float* adpt_w1 = (const float*)d_in[4];
  const float* adpt_w2 = (const float*)d_in[5];
  const float* dh_w1 = (const float*)d_in[6];
  const float* dh_b1 = (const float*)d_in[7];
  const float* dh_g2 = (const float*)d_in[8];
  const float* dh_be2 = (const float*)d_in[9];
  const float* dh_w2 = (const float*)d_in[10];
  const float* dh_b2 = (const float*)d_in[11];
  const float* dh_g3 = (const float*)d_in[12];
  const float* dh_be3 = (const float*)d_in[13];
  const float* dh_w3 = (const float*)d_in[14];
  const float* dh_b3 = (const float*)d_in[15];
  const float* dr_w1 = (const float*)d_in[16];
  const float* dr_b1 = (const float*)d_in[17];
  const float* dr_g2 = (const float*)d_in[18];
  const float* dr_be2 = (const float*)d_in[19];
  const float* dr_w2 = (const float*)d_in[20];
  const float* dr_b2 = (const float*)d_in[21];
  const float* dr_g3 = (const float*)d_in[22];
  const float* dr_be3 = (const float*)d_in[23];
  const float* dr_w3 = (const float*)d_in[24];
  const float* dr_b3 = (const float*)d_in[25];

  // ws layout (bytes)
  const size_t QB_BYTES = (size_t)MPAD * D_DIM * 2;      // 18,513,920
  const size_t RB_BYTES = (size_t)NPAD * D_DIM * 2;      //  4,751,360
  char* ws = (char*)d_ws;
  unsigned short* qb = (unsigned short*)(ws);
  unsigned short* rb = (unsigned short*)(ws + QB_BYTES);
  float* qinv        = (float*)(ws + QB_BYTES + RB_BYTES);
  unsigned* rowmax   = (unsigned*)(ws + QB_BYTES + RB_BYTES + (size_t)M_REAL * 4);
  float* h1          = (float*)(ws + QB_BYTES + RB_BYTES + (size_t)M_REAL * 4 + (size_t)MPAD * 4);

  stage_all_kernel<<<ABLKS + QBLKS + RBLKS, 256, 0, stream>>>(
      q_patch, r_patch, r_img, adpt_w1, qb, rb, qinv, rowmax, h1);
  sim_max_kernel<<<8 * MCHUNK * NTILES, 256, 0, stream>>>(qb, rb, rowmax);
  finale_kernel<<<B_DIM, 256, 0, stream>>>(
      rowmax, qinv, q_img, h1, adpt_w2,
      dh_w1, dh_b1, dh_g2, dh_be2, dh_w2, dh_b2, dh_g3, dh_be3, dh_w3, dh_b3,
      dr_w1, dr_b1, dr_g2, dr_be2, dr_w2, dr_b2, dr_g3, dr_be3, dr_w3, dr_b3,
      (float*)d_out);
}

// Round 5
// 316.375 us; speedup vs baseline: 1.1042x; 1.1042x over previous
//
#include <hip/hip_runtime.h>
#include <stdint.h>

// ---------------- problem dims ----------------
#define B_DIM 64
#define P_DIM 225
#define K_DIM 16
#define D_DIM 640
#define M_REAL (B_DIM * P_DIM)   // 14400 query rows
#define N_REAL (K_DIM * P_DIM)   // 3600 reference rows

// ---------------- GEMM tiling ----------------
#define BM 128
#define BN 128
#define MTILES 113               // ceil(14400/128) -> Mpad 14464
#define NTILES 29                // ceil(3600/128)  -> Npad 3712
#define MPAD (MTILES * BM)
#define NPAD (NTILES * BN)
#define MCHUNK 15                // ceil(MTILES/8) per-XCD bm groups

typedef __bf16 bf16x8 __attribute__((ext_vector_type(8)));
typedef float f32x4 __attribute__((ext_vector_type(4)));

// ---------------- helpers ----------------
__device__ __forceinline__ unsigned short f2bf(float f) {
  union { float f; unsigned u; } v; v.f = f;
  unsigned u = v.u;
  return (unsigned short)((u + 0x7FFFu + ((u >> 16) & 1u)) >> 16);  // RNE
}

// monotone float -> uint key (order-preserving), for atomicMax on floats
__device__ __forceinline__ unsigned f2key(float f) {
  union { float f; unsigned u; } v; v.f = f;
  unsigned u = v.u;
  return (u & 0x80000000u) ? ~u : (u | 0x80000000u);
}
__device__ __forceinline__ float key2f(unsigned k) {
  unsigned b = (k & 0x80000000u) ? (k ^ 0x80000000u) : ~k;
  union { unsigned u; float f; } v; v.u = b;
  return v.f;
}

__device__ __forceinline__ void gl_lds16(const void* g, void* l) {
  __builtin_amdgcn_global_load_lds(
      (const __attribute__((address_space(1))) void*)g,
      (__attribute__((address_space(3))) void*)l,
      16, 0, 0);
}

// =====================================================================
// Kernel A:
//   blocks [0,16)                : adapter stage 1 (first so they start
//                                  at t=0 and hide under staging blocks)
//                                  h1[k][j] = relu(r_img[k] . w1[:,j])
//   blocks [16, 16+QBLKS)        : q rows, 4 per block (+rowmax zero)
//   blocks [16+QBLKS, ...+RBLKS) : r rows, 4 per block
// =====================================================================
#define QBLKS (MPAD / 4)
#define RBLKS (NPAD / 4)
#define ABLKS 16
__global__ __launch_bounds__(256) void stage_all_kernel(
    const float* __restrict__ q, const float* __restrict__ r,
    const float* __restrict__ r_img, const float* __restrict__ aw1,
    unsigned short* __restrict__ qb, unsigned short* __restrict__ rb,
    float* __restrict__ qinv, unsigned* __restrict__ rowmax,
    float* __restrict__ h1) {
  const int blk = blockIdx.x;
  const int tid = threadIdx.x;

  if (blk < ABLKS) {
    // ---- adapter stage 1: one block per k, thread j owns one column ----
    __shared__ float rk_s[D_DIM];
    const int k = blk;
    for (int i = tid; i < D_DIM; i += 256) rk_s[i] = r_img[k * D_DIM + i];
    __syncthreads();
    if (tid < 160) {
      const int j = tid;
      float a = 0.f;
#pragma unroll 8
      for (int d = 0; d < D_DIM; d++) a += rk_s[d] * aw1[d * 160 + j];
      h1[k * 160 + j] = fmaxf(a, 0.f);
    }
    return;
  }

  if (blk < ABLKS + QBLKS) {
    int row = (blk - ABLKS) * 4 + (tid >> 6);
    int lane = tid & 63;
    if (lane == 0) rowmax[row] = 0u;  // key-space minimum
    unsigned short* dst = qb + (long)row * D_DIM;
    if (row >= M_REAL) {
#pragma unroll
      for (int i = 0; i < 10; i++) dst[i * 64 + lane] = 0;
      return;
    }
    const float* src = q + (long)row * D_DIM;
    float v[10];
    float ss = 0.f;
#pragma unroll
    for (int i = 0; i < 10; i++) { v[i] = src[i * 64 + lane]; ss += v[i] * v[i]; }
#pragma unroll
    for (int off = 32; off > 0; off >>= 1) ss += __shfl_xor(ss, off);
    float inv = 1.f / (sqrtf(ss) + 1e-6f);
    if (lane == 0) qinv[row] = inv;
#pragma unroll
    for (int i = 0; i < 10; i++) dst[i * 64 + lane] = f2bf(v[i]);
    return;
  }

  {
    int row = (blk - ABLKS - QBLKS) * 4 + (tid >> 6);
    int lane = tid & 63;
    unsigned short* dst = rb + (long)row * D_DIM;
    if (row >= N_REAL) {
#pragma unroll
      for (int i = 0; i < 10; i++) dst[i * 64 + lane] = 0;
      return;
    }
    const float* src = r + (long)row * D_DIM;
    float v[10];
    float ss = 0.f;
#pragma unroll
    for (int i = 0; i < 10; i++) { v[i] = src[i * 64 + lane]; ss += v[i] * v[i]; }
#pragma unroll
    for (int off = 32; off > 0; off >>= 1) ss += __shfl_xor(ss, off);
    float sc = 1.f / (sqrtf(ss) + 1e-6f);
#pragma unroll
    for (int i = 0; i < 10; i++) dst[i * 64 + lane] = f2bf(v[i] * sc);
  }
}

// =====================================================================
// Kernel B: fused bf16 MFMA GEMM + row-max.
//   BK=64 as two stacked BK=32 sub-tiles (m97 geometry per sub-tile):
//   halves barrier count (10 K-iters, 32 MFMA per barrier pair) without
//   changing the global_load_lds lane-contiguity or LDS read pattern.
//   XCD-ownership swizzle with bm-fastest order: per XCD, Q-subset
//   (15 tiles, 2.4 MB) + one R-tile stay L2-resident.
// =====================================================================
__global__ __launch_bounds__(256) void sim_max_kernel(
    const unsigned short* __restrict__ Qb,
    const unsigned short* __restrict__ Rb,
    unsigned* __restrict__ rowmax) {
  __shared__ __attribute__((aligned(16))) unsigned short As[2][BM * 32];  // 2x8 KB
  __shared__ __attribute__((aligned(16))) unsigned short Bs[2][BN * 32];  // 2x8 KB

  const int xcd = blockIdx.x & 7;
  const int idx = blockIdx.x >> 3;
  const int bm = xcd + 8 * (idx % MCHUNK);   // bm fastest within XCD
  const int bn = idx / MCHUNK;
  if (bm >= MTILES) return;

  const int tid = threadIdx.x;
  const int wave = tid >> 6, lane = tid & 63;
  const int wr = wave >> 1, wc = wave & 1;
  const int q = lane >> 4, m0 = lane & 15;

  // staging geometry (per 8 KB sub-tile): chunk c of wave ->
  // LDS bytes [((wave*2+c)*64+lane)*16, +16); row stride 32 bf16 = 64 B
  const int fA0 = ((wave * 2 + 0) * 64 + lane) * 16;
  const int fA1 = ((wave * 2 + 1) * 64 + lane) * 16;
  const int rowA0 = fA0 >> 6, colA0 = (fA0 & 63) >> 1;
  const int rowA1 = fA1 >> 6, colA1 = (fA1 & 63) >> 1;

  const int aBase = bm * BM;
  const int bBase = bn * BN;

  f32x4 zero = {0.f, 0.f, 0.f, 0.f};
  f32x4 acc[4][4];
#pragma unroll
  for (int i = 0; i < 4; i++)
#pragma unroll
    for (int j = 0; j < 4; j++) acc[i][j] = zero;

  for (int k0 = 0; k0 < D_DIM; k0 += 64) {
#pragma unroll
    for (int h = 0; h < 2; h++) {
      gl_lds16(Qb + (aBase + rowA0) * D_DIM + k0 + h * 32 + colA0, &As[h][fA0 / 2]);
      gl_lds16(Qb + (aBase + rowA1) * D_DIM + k0 + h * 32 + colA1, &As[h][fA1 / 2]);
      gl_lds16(Rb + (bBase + rowA0) * D_DIM + k0 + h * 32 + colA0, &Bs[h][fA0 / 2]);
      gl_lds16(Rb + (bBase + rowA1) * D_DIM + k0 + h * 32 + colA1, &Bs[h][fA1 / 2]);
    }
    __syncthreads();  // drains vmcnt -> both LDS sub-tiles ready

#pragma unroll
    for (int h = 0; h < 2; h++) {
      bf16x8 af[4], bfr[4];
#pragma unroll
      for (int mi = 0; mi < 4; mi++)
        af[mi] = *(const bf16x8*)&As[h][(wr * 64 + mi * 16 + m0) * 32 + q * 8];
#pragma unroll
      for (int ni = 0; ni < 4; ni++)
        bfr[ni] = *(const bf16x8*)&Bs[h][(wc * 64 + ni * 16 + m0) * 32 + q * 8];
#pragma unroll
      for (int mi = 0; mi < 4; mi++)
#pragma unroll
        for (int ni = 0; ni < 4; ni++)
          acc[mi][ni] = __builtin_amdgcn_mfma_f32_16x16x32_bf16(
              af[mi], bfr[ni], acc[mi][ni], 0, 0, 0);
    }
    __syncthreads();  // protect LDS before next-iter overwrite
  }

  // epilogue: per-row max over this block's 128 columns, then global atomicMax
  const int colBase = bn * BN + wc * 64;
#pragma unroll
  for (int mi = 0; mi < 4; mi++) {
    float rmax[4] = {-3.0e38f, -3.0e38f, -3.0e38f, -3.0e38f};
#pragma unroll
    for (int ni = 0; ni < 4; ni++) {
      bool valid = (colBase + ni * 16 + m0) < N_REAL;
#pragma unroll
      for (int r = 0; r < 4; r++) {
        float v = valid ? acc[mi][ni][r] : -3.0e38f;
        rmax[r] = fmaxf(rmax[r], v);
      }
    }
#pragma unroll
    for (int r = 0; r < 4; r++) {
      float v = rmax[r];
      v = fmaxf(v, __shfl_xor(v, 1));
      v = fmaxf(v, __shfl_xor(v, 2));
      v = fmaxf(v, __shfl_xor(v, 4));
      v = fmaxf(v, __shfl_xor(v, 8));
      rmax[r] = v;
    }
    if (m0 == 0) {
      int row = bm * BM + wr * 64 + mi * 16 + q * 4;
#pragma unroll
      for (int r = 0; r < 4; r++)
        atomicMax(&rowmax[row + r], f2key(rmax[r]));
    }
  }
}

// =====================================================================
// Kernel C: finale — per batch element b:
//   amap + amean + s_map head + (favg from h1, redundant per block) +
//   s_ref head + final score. 64 blocks x 256.
// =====================================================================
__global__ __launch_bounds__(256) void finale_kernel(
    const unsigned* __restrict__ rowmax, const float* __restrict__ qinv,
    const float* __restrict__ q_img, const float* __restrict__ h1,
    const float* __restrict__ aw2,
    const float* __restrict__ hw1, const float* __restrict__ hb1,
    const float* __restrict__ hg2, const float* __restrict__ hbe2,
    const float* __restrict__ hw2, const float* __restrict__ hb2,
    const float* __restrict__ hg3, const float* __restrict__ hbe3,
    const float* __restrict__ hw3, const float* __restrict__ hb3,
    const float* __restrict__ rw1, const float* __restrict__ rb1,
    const float* __restrict__ rg2, const float* __restrict__ rbe2,
    const float* __restrict__ rw2, const float* __restrict__ rb2,
    const float* __restrict__ rg3, const float* __restrict__ rbe3,
    const float* __restrict__ rw3, const float* __restrict__ rb3,
    float* __restrict__ out) {
  int b = blockIdx.x, t = threadIdx.x;
  __shared__ float h1a[16 * 160];   // adapter hidden (10 KB)
  __shared__ float amap[P_DIM];
  __shared__ float red[256];
  __shared__ float x[D_DIM];
  __shared__ float h1s[128];
  __shared__ float h2s[64];
  __shared__ float smap_s;

  // load adapter hidden into LDS
#pragma unroll
  for (int i = 0; i < 10; i++) h1a[i * 256 + t] = h1[i * 256 + t];

  // amap
  float av = 0.f;
  if (t < P_DIM) {
    int row = b * P_DIM + t;
    float mx = key2f(rowmax[row]);
    av = 0.5f * (1.f - mx * qinv[row]);
    amap[t] = av;
  }
  red[t] = av;
  __syncthreads();
  for (int s = 128; s > 0; s >>= 1) {
    if (t < s) red[t] += red[t + s];
    __syncthreads();
  }
  float amean = red[0] * (1.f / 225.f);  // uniform after reduction

  // ---- s_map head (input amap, 225) ----
  if (t < 128) {
    float a0 = hb1[t], a1 = 0.f, a2 = 0.f;
#pragma unroll 5
    for (int p = 0; p < P_DIM; p += 3) {  // 225 = 75*3
      a0 += amap[p + 0] * hw1[(p + 0) * 128 + t];
      a1 += amap[p + 1] * hw1[(p + 1) * 128 + t];
      a2 += amap[p + 2] * hw1[(p + 2) * 128 + t];
    }
    float a = a0 + a1 + a2;
    h1s[t] = fmaxf(a, 0.f) * hg2[t] + hbe2[t];
  }
  __syncthreads();
  if (t < 64) {
    float a = hb2[t];
#pragma unroll 8
    for (int j = 0; j < 128; j++) a += h1s[j] * hw2[j * 64 + t];
    h2s[t] = fmaxf(a, 0.f) * hg3[t] + hbe3[t];
  }
  __syncthreads();
  if (t < 64) {
    float p = h2s[t] * hw3[t];
    p += __shfl_xor(p, 32); p += __shfl_xor(p, 16); p += __shfl_xor(p, 8);
    p += __shfl_xor(p, 4);  p += __shfl_xor(p, 2);  p += __shfl_xor(p, 1);
    if (t == 0) smap_s = 1.f / (1.f + expf(-(p + hb3[0])));
  }
  __syncthreads();

  // ---- adapter stage 2 (redundant per block): x[d] = q_img[b][d] - favg[d]
  for (int d = t; d < D_DIM; d += 256) {
    float a[K_DIM];
#pragma unroll
    for (int k = 0; k < K_DIM; k++) a[k] = 0.f;
#pragma unroll 4
    for (int j = 0; j < 160; j++) {
      float w = aw2[j * D_DIM + d];
#pragma unroll
      for (int k = 0; k < K_DIM; k++) a[k] += h1a[k * 160 + j] * w;
    }
    float s = 0.f;
#pragma unroll
    for (int k = 0; k < K_DIM; k++) s += fmaxf(a[k], 0.f);
    x[d] = q_img[b * D_DIM + d] - s * (1.f / 16.f);
  }
  __syncthreads();

  // ---- s_ref head (input x, 640) ----
  if (t < 128) {
    float a0 = rb1[t], a1 = 0.f, a2 = 0.f, a3 = 0.f;
#pragma unroll 4
    for (int d = 0; d < D_DIM; d += 4) {
      a0 += x[d + 0] * rw1[(d + 0) * 128 + t];
      a1 += x[d + 1] * rw1[(d + 1) * 128 + t];
      a2 += x[d + 2] * rw1[(d + 2) * 128 + t];
      a3 += x[d + 3] * rw1[(d + 3) * 128 + t];
    }
    float a = a0 + a1 + a2 + a3;
    h1s[t] = fmaxf(a, 0.f) * rg2[t] + rbe2[t];
  }
  __syncthreads();
  if (t < 64) {
    float a = rb2[t];
#pragma unroll 8
    for (int j = 0; j < 128; j++) a += h1s[j] * rw2[j * 64 + t];
    h2s[t] = fmaxf(a, 0.f) * rg3[t] + rbe3[t];
  }
  __syncthreads();
  if (t < 64) {
    float p = h2s[t] * rw3[t];
    p += __shfl_xor(p, 32); p += __shfl_xor(p, 16); p += __shfl_xor(p, 8);
    p += __shfl_xor(p, 4);  p += __shfl_xor(p, 2);  p += __shfl_xor(p, 1);
    if (t == 0) {
      float sref = 1.f / (1.f + expf(-(p + rb3[0])));
      out[b] = 0.5f * (sref + smap_s) + amean;
    }
  }
}

// ---------------- launch ----------------
extern "C" void kernel_launch(void* const* d_in, const int* in_sizes, int n_in,
                              void* d_out, int out_size, void* d_ws, size_t ws_size,
                              hipStream_t stream) {
  const float* q_patch = (const float*)d_in[0];
  const float* r_patch = (const float*)d_in[1];
  const float* q_img   = (const float*)d_in[2];
  const float* r_img   = (const float*)d_in[3];
  const float* adpt_w1 = (const float*)d_in[4];
  const float* adpt_w2 = (const float*)d_in[5];
  const float* dh_w1 = (const float*)d_in[6];
  const float* dh_b1 = (const float*)d_in[7];
  const float* dh_g2 = (const float*)d_in[8];
  const float* dh_be2 = (const float*)d_in[9];
  const float* dh_w2 = (const float*)d_in[10];
  const float* dh_b2 = (const float*)d_in[11];
  const float* dh_g3 = (const float*)d_in[12];
  const float* dh_be3 = (const float*)d_in[13];
  const float* dh_w3 = (const float*)d_in[14];
  const float* dh_b3 = (const float*)d_in[15];
  const float* dr_w1 = (const float*)d_in[16];
  const float* dr_b1 = (const float*)d_in[17];
  const float* dr_g2 = (const float*)d_in[18];
  const float* dr_be2 = (const float*)d_in[19];
  const float* dr_w2 = (const float*)d_in[20];
  const float* dr_b2 = (const float*)d_in[21];
  const float* dr_g3 = (const float*)d_in[22];
  const float* dr_be3 = (const float*)d_in[23];
  const float* dr_w3 = (const float*)d_in[24];
  const float* dr_b3 = (const float*)d_in[25];

  // ws layout (bytes)
  const size_t QB_BYTES = (size_t)MPAD * D_DIM * 2;      // 18,513,920
  const size_t RB_BYTES = (size_t)NPAD * D_DIM * 2;      //  4,751,360
  char* ws = (char*)d_ws;
  unsigned short* qb = (unsigned short*)(ws);
  unsigned short* rb = (unsigned short*)(ws + QB_BYTES);
  float* qinv        = (float*)(ws + QB_BYTES + RB_BYTES);
  unsigned* rowmax   = (unsigned*)(ws + QB_BYTES + RB_BYTES + (size_t)M_REAL * 4);
  float* h1          = (float*)(ws + QB_BYTES + RB_BYTES + (size_t)M_REAL * 4 + (size_t)MPAD * 4);

  stage_all_kernel<<<ABLKS + QBLKS + RBLKS, 256, 0, stream>>>(
      q_patch, r_patch, r_img, adpt_w1, qb, rb, qinv, rowmax, h1);
  sim_max_kernel<<<8 * MCHUNK * NTILES, 256, 0, stream>>>(qb, rb, rowmax);
  finale_kernel<<<B_DIM, 256, 0, stream>>>(
      rowmax, qinv, q_img, h1, adpt_w2,
      dh_w1, dh_b1, dh_g2, dh_be2, dh_w2, dh_b2, dh_g3, dh_be3, dh_w3, dh_b3,
      dr_w1, dr_b1, dr_g2, dr_be2, dr_w2, dr_b2, dr_g3, dr_be3, dr_w3, dr_b3,
      (float*)d_out);
}

// Round 6
// 295.230 us; speedup vs baseline: 1.1833x; 1.0716x over previous
//
#include <hip/hip_runtime.h>
#include <stdint.h>

// ---------------- problem dims ----------------
#define B_DIM 64
#define P_DIM 225
#define K_DIM 16
#define D_DIM 640
#define M_REAL (B_DIM * P_DIM)   // 14400 query rows
#define N_REAL (K_DIM * P_DIM)   // 3600 reference rows

// ---------------- GEMM tiling ----------------
#define BM 128
#define BN 128
#define MTILES 113               // ceil(14400/128) -> Mpad 14464
#define NTILES 29                // ceil(3600/128)  -> Npad 3712
#define MPAD (MTILES * BM)
#define NPAD (NTILES * BN)
#define MCHUNK 15                // ceil(MTILES/8) per-XCD bm groups

typedef __bf16 bf16x8 __attribute__((ext_vector_type(8)));
typedef float f32x4 __attribute__((ext_vector_type(4)));

// ---------------- helpers ----------------
__device__ __forceinline__ unsigned short f2bf(float f) {
  union { float f; unsigned u; } v; v.f = f;
  unsigned u = v.u;
  return (unsigned short)((u + 0x7FFFu + ((u >> 16) & 1u)) >> 16);  // RNE
}

__device__ __forceinline__ unsigned f2key(float f) {
  union { float f; unsigned u; } v; v.f = f;
  unsigned u = v.u;
  return (u & 0x80000000u) ? ~u : (u | 0x80000000u);
}
__device__ __forceinline__ float key2f(unsigned k) {
  unsigned b = (k & 0x80000000u) ? (k ^ 0x80000000u) : ~k;
  union { unsigned u; float f; } v; v.u = b;
  return v.f;
}

__device__ __forceinline__ void gl_lds16(const void* g, void* l) {
  __builtin_amdgcn_global_load_lds(
      (const __attribute__((address_space(1))) void*)g,
      (__attribute__((address_space(3))) void*)l,
      16, 0, 0);
}

__device__ __forceinline__ float sigmoidf(float x) {
  return 1.f / (1.f + expf(-x));
}

// =====================================================================
// Kernel A: staging (unchanged from round 5)
// =====================================================================
#define QBLKS (MPAD / 4)
#define RBLKS (NPAD / 4)
#define ABLKS 16
__global__ __launch_bounds__(256) void stage_all_kernel(
    const float* __restrict__ q, const float* __restrict__ r,
    const float* __restrict__ r_img, const float* __restrict__ aw1,
    unsigned short* __restrict__ qb, unsigned short* __restrict__ rb,
    float* __restrict__ qinv, unsigned* __restrict__ rowmax,
    float* __restrict__ h1) {
  const int blk = blockIdx.x;
  const int tid = threadIdx.x;

  if (blk < ABLKS) {
    __shared__ float rk_s[D_DIM];
    const int k = blk;
    for (int i = tid; i < D_DIM; i += 256) rk_s[i] = r_img[k * D_DIM + i];
    __syncthreads();
    if (tid < 160) {
      const int j = tid;
      float a = 0.f;
#pragma unroll 8
      for (int d = 0; d < D_DIM; d++) a += rk_s[d] * aw1[d * 160 + j];
      h1[k * 160 + j] = fmaxf(a, 0.f);
    }
    return;
  }

  if (blk < ABLKS + QBLKS) {
    int row = (blk - ABLKS) * 4 + (tid >> 6);
    int lane = tid & 63;
    if (lane == 0) rowmax[row] = 0u;
    unsigned short* dst = qb + (long)row * D_DIM;
    if (row >= M_REAL) {
#pragma unroll
      for (int i = 0; i < 10; i++) dst[i * 64 + lane] = 0;
      return;
    }
    const float* src = q + (long)row * D_DIM;
    float v[10];
    float ss = 0.f;
#pragma unroll
    for (int i = 0; i < 10; i++) { v[i] = src[i * 64 + lane]; ss += v[i] * v[i]; }
#pragma unroll
    for (int off = 32; off > 0; off >>= 1) ss += __shfl_xor(ss, off);
    float inv = 1.f / (sqrtf(ss) + 1e-6f);
    if (lane == 0) qinv[row] = inv;
#pragma unroll
    for (int i = 0; i < 10; i++) dst[i * 64 + lane] = f2bf(v[i]);
    return;
  }

  {
    int row = (blk - ABLKS - QBLKS) * 4 + (tid >> 6);
    int lane = tid & 63;
    unsigned short* dst = rb + (long)row * D_DIM;
    if (row >= N_REAL) {
#pragma unroll
      for (int i = 0; i < 10; i++) dst[i * 64 + lane] = 0;
      return;
    }
    const float* src = r + (long)row * D_DIM;
    float v[10];
    float ss = 0.f;
#pragma unroll
    for (int i = 0; i < 10; i++) { v[i] = src[i * 64 + lane]; ss += v[i] * v[i]; }
#pragma unroll
    for (int off = 32; off > 0; off >>= 1) ss += __shfl_xor(ss, off);
    float sc = 1.f / (sqrtf(ss) + 1e-6f);
#pragma unroll
    for (int i = 0; i < 10; i++) dst[i * 64 + lane] = f2bf(v[i] * sc);
  }
}

// =====================================================================
// Kernel B: fused bf16 MFMA GEMM + row-max (round-5 BK=64 version)
// =====================================================================
__global__ __launch_bounds__(256) void sim_max_kernel(
    const unsigned short* __restrict__ Qb,
    const unsigned short* __restrict__ Rb,
    unsigned* __restrict__ rowmax) {
  __shared__ __attribute__((aligned(16))) unsigned short As[2][BM * 32];
  __shared__ __attribute__((aligned(16))) unsigned short Bs[2][BN * 32];

  const int xcd = blockIdx.x & 7;
  const int idx = blockIdx.x >> 3;
  const int bm = xcd + 8 * (idx % MCHUNK);
  const int bn = idx / MCHUNK;
  if (bm >= MTILES) return;

  const int tid = threadIdx.x;
  const int wave = tid >> 6, lane = tid & 63;
  const int wr = wave >> 1, wc = wave & 1;
  const int q = lane >> 4, m0 = lane & 15;

  const int fA0 = ((wave * 2 + 0) * 64 + lane) * 16;
  const int fA1 = ((wave * 2 + 1) * 64 + lane) * 16;
  const int rowA0 = fA0 >> 6, colA0 = (fA0 & 63) >> 1;
  const int rowA1 = fA1 >> 6, colA1 = (fA1 & 63) >> 1;

  const int aBase = bm * BM;
  const int bBase = bn * BN;

  f32x4 zero = {0.f, 0.f, 0.f, 0.f};
  f32x4 acc[4][4];
#pragma unroll
  for (int i = 0; i < 4; i++)
#pragma unroll
    for (int j = 0; j < 4; j++) acc[i][j] = zero;

  for (int k0 = 0; k0 < D_DIM; k0 += 64) {
#pragma unroll
    for (int h = 0; h < 2; h++) {
      gl_lds16(Qb + (aBase + rowA0) * D_DIM + k0 + h * 32 + colA0, &As[h][fA0 / 2]);
      gl_lds16(Qb + (aBase + rowA1) * D_DIM + k0 + h * 32 + colA1, &As[h][fA1 / 2]);
      gl_lds16(Rb + (bBase + rowA0) * D_DIM + k0 + h * 32 + colA0, &Bs[h][fA0 / 2]);
      gl_lds16(Rb + (bBase + rowA1) * D_DIM + k0 + h * 32 + colA1, &Bs[h][fA1 / 2]);
    }
    __syncthreads();

#pragma unroll
    for (int h = 0; h < 2; h++) {
      bf16x8 af[4], bfr[4];
#pragma unroll
      for (int mi = 0; mi < 4; mi++)
        af[mi] = *(const bf16x8*)&As[h][(wr * 64 + mi * 16 + m0) * 32 + q * 8];
#pragma unroll
      for (int ni = 0; ni < 4; ni++)
        bfr[ni] = *(const bf16x8*)&Bs[h][(wc * 64 + ni * 16 + m0) * 32 + q * 8];
#pragma unroll
      for (int mi = 0; mi < 4; mi++)
#pragma unroll
        for (int ni = 0; ni < 4; ni++)
          acc[mi][ni] = __builtin_amdgcn_mfma_f32_16x16x32_bf16(
              af[mi], bfr[ni], acc[mi][ni], 0, 0, 0);
    }
    __syncthreads();
  }

  const int colBase = bn * BN + wc * 64;
#pragma unroll
  for (int mi = 0; mi < 4; mi++) {
    float rmax[4] = {-3.0e38f, -3.0e38f, -3.0e38f, -3.0e38f};
#pragma unroll
    for (int ni = 0; ni < 4; ni++) {
      bool valid = (colBase + ni * 16 + m0) < N_REAL;
#pragma unroll
      for (int r = 0; r < 4; r++) {
        float v = valid ? acc[mi][ni][r] : -3.0e38f;
        rmax[r] = fmaxf(rmax[r], v);
      }
    }
#pragma unroll
    for (int r = 0; r < 4; r++) {
      float v = rmax[r];
      v = fmaxf(v, __shfl_xor(v, 1));
      v = fmaxf(v, __shfl_xor(v, 2));
      v = fmaxf(v, __shfl_xor(v, 4));
      v = fmaxf(v, __shfl_xor(v, 8));
      rmax[r] = v;
    }
    if (m0 == 0) {
      int row = bm * BM + wr * 64 + mi * 16 + q * 4;
#pragma unroll
      for (int r = 0; r < 4; r++)
        atomicMax(&rowmax[row + r], f2key(rmax[r]));
    }
  }
}

// =====================================================================
// Kernel T1: tail part 1.
//   blocks 0..9   : favg[d0..d0+64) — aw2 tile (160x64=40KB) LDS-staged
//   blocks 10..17 : map-head L1 for 8 batch each (hw1 p-tiles staged,
//                   each weight reused 8x) + amean[b]
// =====================================================================
__global__ __launch_bounds__(256) void tail1_kernel(
    const float* __restrict__ h1, const float* __restrict__ aw2,
    const unsigned* __restrict__ rowmax, const float* __restrict__ qinv,
    const float* __restrict__ hw1, const float* __restrict__ hb1,
    const float* __restrict__ hg2, const float* __restrict__ hbe2,
    float* __restrict__ favg, float* __restrict__ h1m,
    float* __restrict__ amean) {
  __shared__ __attribute__((aligned(16))) float S[12800];  // 51.2 KB
  const int blk = blockIdx.x;
  const int tid = threadIdx.x;
  const int wave = tid >> 6, lane = tid & 63;

  if (blk < 10) {
    // ---------- favg for d in [d0, d0+64) ----------
    const int d0 = blk * 64;
    // h1 (16x160 = 2560 fl) -> S[0..2560)
#pragma unroll
    for (int i = 0; i < 10; i++) S[i * 256 + tid] = h1[i * 256 + tid];
    // aw2 tile [160 j][64 d] -> S[2560..12800) via global_load_lds
    // chunk e = c*256 + tid; row = e>>4 (64 fl = 16 chunks), col16 = e&15
#pragma unroll
    for (int c = 0; c < 10; c++) {
      int e = c * 256 + tid;
      int row = e >> 4, col16 = e & 15;
      gl_lds16((const char*)aw2 + (size_t)row * D_DIM * 4 + d0 * 4 + col16 * 16,
               (char*)&S[2560] + e * 16);
    }
    __syncthreads();

    const int d = tid & 63, kg = tid >> 6;  // kg covers k = kg*4 .. kg*4+3
    float a0 = 0.f, a1 = 0.f, a2 = 0.f, a3 = 0.f;
#pragma unroll 8
    for (int j = 0; j < 160; j++) {
      float w = S[2560 + j * 64 + d];
      a0 += S[(kg * 4 + 0) * 160 + j] * w;
      a1 += S[(kg * 4 + 1) * 160 + j] * w;
      a2 += S[(kg * 4 + 2) * 160 + j] * w;
      a3 += S[(kg * 4 + 3) * 160 + j] * w;
    }
    float p = fmaxf(a0, 0.f) + fmaxf(a1, 0.f) + fmaxf(a2, 0.f) + fmaxf(a3, 0.f);
    __syncthreads();
    S[kg * 64 + d] = p;  // reuse h1 region for reduction
    __syncthreads();
    if (kg == 0)
      favg[d0 + d] = (S[d] + S[64 + d] + S[128 + d] + S[192 + d]) * (1.f / 16.f);
    return;
  }

  // ---------- map-head L1 + amean, 8 batch per block ----------
  const int bO = (blk - 10) * 8;
  // amap_s [8][225] -> S[0..1800)
  for (int e = tid; e < 8 * P_DIM; e += 256) {
    int row = bO * P_DIM + e;
    float mx = key2f(rowmax[row]);
    S[e] = 0.5f * (1.f - mx * qinv[row]);
  }
  __syncthreads();

  // amean: wave w handles b = w*2, w*2+1
#pragma unroll
  for (int i = 0; i < 2; i++) {
    int b = wave * 2 + i;
    float s = S[b * P_DIM + lane];
    s += S[b * P_DIM + lane + 64];
    s += S[b * P_DIM + lane + 128];
    if (lane < 33) s += S[b * P_DIM + lane + 192];
#pragma unroll
    for (int off = 32; off > 0; off >>= 1) s += __shfl_xor(s, off);
    if (lane == 0) amean[bO + b] = s * (1.f / 225.f);
  }

  const int j = tid & 127, bh = tid >> 7;  // bh: 2 groups of 4 batch
  float acc[4];
#pragma unroll
  for (int bb = 0; bb < 4; bb++) acc[bb] = hb1[j];

  // 7 tiles of 32 p-rows (224), staged at S[1800..5896)
  for (int t = 0; t < 7; t++) {
    int p0 = t * 32;
    // stage hw1[p0..p0+32)[128] = 4096 fl: e = c*256+tid; row=e>>5, col16=e&31
#pragma unroll
    for (int c = 0; c < 4; c++) {
      int e = c * 256 + tid;
      int row = e >> 5, col16 = e & 31;
      gl_lds16((const char*)hw1 + (size_t)(p0 + row) * 128 * 4 + col16 * 16,
               (char*)&S[1800] + e * 16);
    }
    __syncthreads();
#pragma unroll 4
    for (int pr = 0; pr < 32; pr++) {
      float w = S[1800 + pr * 128 + j];
#pragma unroll
      for (int bb = 0; bb < 4; bb++)
        acc[bb] += S[(bh * 4 + bb) * P_DIM + p0 + pr] * w;
    }
    __syncthreads();
  }
  // last row p = 224
  {
    float w = hw1[224 * 128 + j];
#pragma unroll
    for (int bb = 0; bb < 4; bb++)
      acc[bb] += S[(bh * 4 + bb) * P_DIM + 224] * w;
  }
#pragma unroll
  for (int bb = 0; bb < 4; bb++) {
    float h = fmaxf(acc[bb], 0.f) * hg2[j] + hbe2[j];
    h1m[(bO + bh * 4 + bb) * 128 + j] = h;
  }
}

// =====================================================================
// Kernel T2: tail part 2 — 8 blocks x 8 batch:
//   ref-head L1 (rw1 d-tiles double-buffered) -> L2/L3 both heads -> score
// LDS layout (floats):
//   x      @ 0     (5120)   [phase A]
//   tileA  @ 5120  (4096)   [phase A]
//   tileB  @ 9216  (4096)   [phase A]
//   w2_s   @ 0     (8192)   [phase B]
//   h1m_s  @ 8192  (1024)   [phase B]
//   h2r    @ 10240 (512), h2m @ 10752 (512)
//   h1r    @ 13312 (1024)  [written after tiles dead]
//   sref   @ 11264 (8), smap @ 11272 (8)
// =====================================================================
__global__ __launch_bounds__(256) void tail2_kernel(
    const float* __restrict__ q_img, const float* __restrict__ favg,
    const float* __restrict__ h1m, const float* __restrict__ amean,
    const float* __restrict__ hw2, const float* __restrict__ hb2,
    const float* __restrict__ hg3, const float* __restrict__ hbe3,
    const float* __restrict__ hw3, const float* __restrict__ hb3,
    const float* __restrict__ rw1, const float* __restrict__ rb1,
    const float* __restrict__ rg2, const float* __restrict__ rbe2,
    const float* __restrict__ rw2, const float* __restrict__ rb2,
    const float* __restrict__ rg3, const float* __restrict__ rbe3,
    const float* __restrict__ rw3, const float* __restrict__ rb3,
    float* __restrict__ out) {
  __shared__ __attribute__((aligned(16))) float S[14336];  // 57.3 KB
  const int tid = threadIdx.x;
  const int wave = tid >> 6, lane = tid & 63;
  const int bO = blockIdx.x * 8;

  // ---- phase A: x = q_img - favg for 8 batch (8x640 = 5120 fl) ----
#pragma unroll
  for (int i = 0; i < 20; i++) {
    int e = i * 256 + tid;
    int d = e % D_DIM;
    S[e] = q_img[bO * D_DIM + e] - favg[d];
  }

  // stage tile 0 into tileA
#pragma unroll
  for (int c = 0; c < 4; c++) {
    int e = c * 256 + tid;
    int row = e >> 5, col16 = e & 31;
    gl_lds16((const char*)rw1 + (size_t)row * 128 * 4 + col16 * 16,
             (char*)&S[5120] + e * 16);
  }
  __syncthreads();

  const int j = tid & 127, bh = tid >> 7;  // 2 groups of 4 batch
  float acc[4];
#pragma unroll
  for (int bb = 0; bb < 4; bb++) acc[bb] = rb1[j];

  // 20 d-tiles of 32 rows, double-buffered
  for (int t = 0; t < 20; t++) {
    int bufC = 5120 + (t & 1) * 4096;      // compute buffer
    int bufN = 5120 + ((t + 1) & 1) * 4096;  // next stage buffer
    if (t < 19) {
      int d0n = (t + 1) * 32;
#pragma unroll
      for (int c = 0; c < 4; c++) {
        int e = c * 256 + tid;
        int row = e >> 5, col16 = e & 31;
        gl_lds16((const char*)rw1 + (size_t)(d0n + row) * 128 * 4 + col16 * 16,
                 (char*)&S[bufN] + e * 16);
      }
    }
    int d0 = t * 32;
#pragma unroll 4
    for (int dr = 0; dr < 32; dr++) {
      float w = S[bufC + dr * 128 + j];
#pragma unroll
      for (int bb = 0; bb < 4; bb++)
        acc[bb] += S[(bh * 4 + bb) * D_DIM + d0 + dr] * w;
    }
    __syncthreads();  // drains next-tile staging + protects buffers
  }

  // h1r (overwrites dead tile region)
#pragma unroll
  for (int bb = 0; bb < 4; bb++) {
    float h = fmaxf(acc[bb], 0.f) * rg2[j] + rbe2[j];
    S[13312 + (bh * 4 + bb) * 128 + j] = h;
  }
  __syncthreads();

  // ---- phase B: stage rw2 (8192 fl) @0 + load h1m_s @8192 ----
#pragma unroll
  for (int c = 0; c < 8; c++) {
    int e = c * 256 + tid;
    gl_lds16((const char*)rw2 + e * 16, (char*)&S[0] + e * 16);
  }
#pragma unroll
  for (int i = 0; i < 4; i++) {
    int e = i * 256 + tid;
    S[8192 + e] = h1m[bO * 128 + e];
  }
  __syncthreads();

  // ref L2: n = tid&63, bg = tid>>6 -> 2 batch each
  {
    const int n = tid & 63, bg = tid >> 6;
#pragma unroll
    for (int bb = 0; bb < 2; bb++) {
      int b = bg * 2 + bb;
      float a = rb2[n];
#pragma unroll 8
      for (int jj = 0; jj < 128; jj++) a += S[13312 + b * 128 + jj] * S[jj * 64 + n];
      S[10240 + b * 64 + n] = fmaxf(a, 0.f) * rg3[n] + rbe3[n];
    }
  }
  __syncthreads();

  // stage hw2 @0 (overwrites rw2) -- async while ref L3 computes
#pragma unroll
  for (int c = 0; c < 8; c++) {
    int e = c * 256 + tid;
    gl_lds16((const char*)hw2 + e * 16, (char*)&S[0] + e * 16);
  }

  // ref L3: wave handles b = wave*2, wave*2+1
#pragma unroll
  for (int i = 0; i < 2; i++) {
    int b = wave * 2 + i;
    float v = S[10240 + b * 64 + lane] * rw3[lane];
#pragma unroll
    for (int off = 32; off > 0; off >>= 1) v += __shfl_xor(v, off);
    if (lane == 0) S[11264 + b] = sigmoidf(v + rb3[0]);
  }
  __syncthreads();  // drains hw2 staging, orders sref writes

  // map L2
  {
    const int n = tid & 63, bg = tid >> 6;
#pragma unroll
    for (int bb = 0; bb < 2; bb++) {
      int b = bg * 2 + bb;
      float a = hb2[n];
#pragma unroll 8
      for (int jj = 0; jj < 128; jj++) a += S[8192 + b * 128 + jj] * S[jj * 64 + n];
      S[10752 + b * 64 + n] = fmaxf(a, 0.f) * hg3[n] + hbe3[n];
    }
  }
  __syncthreads();

  // map L3
#pragma unroll
  for (int i = 0; i < 2; i++) {
    int b = wave * 2 + i;
    float v = S[10752 + b * 64 + lane] * hw3[lane];
#pragma unroll
    for (int off = 32; off > 0; off >>= 1) v += __shfl_xor(v, off);
    if (lane == 0) S[11272 + b] = sigmoidf(v + hb3[0]);
  }
  __syncthreads();

  if (tid < 8) {
    int b = bO + tid;
    out[b] = 0.5f * (S[11264 + tid] + S[11272 + tid]) + amean[b];
  }
}

// ---------------- launch ----------------
extern "C" void kernel_launch(void* const* d_in, const int* in_sizes, int n_in,
                              void* d_out, int out_size, void* d_ws, size_t ws_size,
                              hipStream_t stream) {
  const float* q_patch = (const float*)d_in[0];
  const float* r_patch = (const float*)d_in[1];
  const float* q_img   = (const float*)d_in[2];
  const float* r_img   = (const float*)d_in[3];
  const float* adpt_w1 = (const float*)d_in[4];
  const float* adpt_w2 = (const float*)d_in[5];
  const float* dh_w1 = (const float*)d_in[6];
  const float* dh_b1 = (const float*)d_in[7];
  const float* dh_g2 = (const float*)d_in[8];
  const float* dh_be2 = (const float*)d_in[9];
  const float* dh_w2 = (const float*)d_in[10];
  const float* dh_b2 = (const float*)d_in[11];
  const float* dh_g3 = (const float*)d_in[12];
  const float* dh_be3 = (const float*)d_in[13];
  const float* dh_w3 = (const float*)d_in[14];
  const float* dh_b3 = (const float*)d_in[15];
  const float* dr_w1 = (const float*)d_in[16];
  const float* dr_b1 = (const float*)d_in[17];
  const float* dr_g2 = (const float*)d_in[18];
  const float* dr_be2 = (const float*)d_in[19];
  const float* dr_w2 = (const float*)d_in[20];
  const float* dr_b2 = (const float*)d_in[21];
  const float* dr_g3 = (const float*)d_in[22];
  const float* dr_be3 = (const float*)d_in[23];
  const float* dr_w3 = (const float*)d_in[24];
  const float* dr_b3 = (const float*)d_in[25];

  // ws layout (bytes)
  const size_t QB_BYTES = (size_t)MPAD * D_DIM * 2;
  const size_t RB_BYTES = (size_t)NPAD * D_DIM * 2;
  char* ws = (char*)d_ws;
  unsigned short* qb = (unsigned short*)(ws);
  unsigned short* rb = (unsigned short*)(ws + QB_BYTES);
  float* qinv        = (float*)(ws + QB_BYTES + RB_BYTES);
  unsigned* rowmax   = (unsigned*)(ws + QB_BYTES + RB_BYTES + (size_t)M_REAL * 4);
  float* h1          = (float*)(ws + QB_BYTES + RB_BYTES + (size_t)M_REAL * 4 + (size_t)MPAD * 4);
  float* favg        = h1 + 16 * 160;
  float* h1m         = favg + D_DIM;
  float* amean       = h1m + 64 * 128;

  stage_all_kernel<<<ABLKS + QBLKS + RBLKS, 256, 0, stream>>>(
      q_patch, r_patch, r_img, adpt_w1, qb, rb, qinv, rowmax, h1);
  sim_max_kernel<<<8 * MCHUNK * NTILES, 256, 0, stream>>>(qb, rb, rowmax);
  tail1_kernel<<<18, 256, 0, stream>>>(
      h1, adpt_w2, rowmax, qinv, dh_w1, dh_b1, dh_g2, dh_be2,
      favg, h1m, amean);
  tail2_kernel<<<8, 256, 0, stream>>>(
      q_img, favg, h1m, amean,
      dh_w2, dh_b2, dh_g3, dh_be3, dh_w3, dh_b3,
      dr_w1, dr_b1, dr_g2, dr_be2, dr_w2, dr_b2, dr_g3, dr_be3, dr_w3, dr_b3,
      (float*)d_out);
}

// Round 7
// 282.448 us; speedup vs baseline: 1.2368x; 1.0453x over previous
//
#include <hip/hip_runtime.h>
#include <stdint.h>

// ---------------- problem dims ----------------
#define B_DIM 64
#define P_DIM 225
#define K_DIM 16
#define D_DIM 640
#define M_REAL (B_DIM * P_DIM)   // 14400 query rows
#define N_REAL (K_DIM * P_DIM)   // 3600 reference rows

// ---------------- GEMM tiling ----------------
#define BM 128
#define BN 128
#define MTILES 113               // ceil(14400/128) -> Mpad 14464
#define NTILES 29                // ceil(3600/128)  -> Npad 3712
#define MPAD (MTILES * BM)
#define NPAD (NTILES * BN)
#define MCHUNK 15                // ceil(MTILES/8) per-XCD bm groups

typedef float f32x4 __attribute__((ext_vector_type(4)));

// ---------------- helpers ----------------
// float -> OCP e4m3 byte (v_cvt_pk_fp8_f32)
__device__ __forceinline__ unsigned char f2fp8(float f) {
  int r = __builtin_amdgcn_cvt_pk_fp8_f32(f, f, 0, false);
  return (unsigned char)(r & 0xFF);
}

// monotone float -> uint key (order-preserving), for atomicMax on floats
__device__ __forceinline__ unsigned f2key(float f) {
  union { float f; unsigned u; } v; v.f = f;
  unsigned u = v.u;
  return (u & 0x80000000u) ? ~u : (u | 0x80000000u);
}
__device__ __forceinline__ float key2f(unsigned k) {
  unsigned b = (k & 0x80000000u) ? (k ^ 0x80000000u) : ~k;
  union { unsigned u; float f; } v; v.u = b;
  return v.f;
}

__device__ __forceinline__ void gl_lds16(const void* g, void* l) {
  __builtin_amdgcn_global_load_lds(
      (const __attribute__((address_space(1))) void*)g,
      (__attribute__((address_space(3))) void*)l,
      16, 0, 0);
}

__device__ __forceinline__ float sigmoidf(float x) {
  return 1.f / (1.f + expf(-x));
}

// =====================================================================
// Kernel A: staging (fp8 e4m3 outputs)
//   q rows: raw cast; qinv stores (1/16)/(||q||+eps)  [16 = r-scale]
//   r rows: L2-normalized then x16 (keeps e4m3 in normal range)
// =====================================================================
#define QBLKS (MPAD / 4)
#define RBLKS (NPAD / 4)
#define ABLKS 16
__global__ __launch_bounds__(256) void stage_all_kernel(
    const float* __restrict__ q, const float* __restrict__ r,
    const float* __restrict__ r_img, const float* __restrict__ aw1,
    unsigned char* __restrict__ qb, unsigned char* __restrict__ rb,
    float* __restrict__ qinv, unsigned* __restrict__ rowmax,
    float* __restrict__ h1) {
  const int blk = blockIdx.x;
  const int tid = threadIdx.x;

  if (blk < ABLKS) {
    __shared__ float rk_s[D_DIM];
    const int k = blk;
    for (int i = tid; i < D_DIM; i += 256) rk_s[i] = r_img[k * D_DIM + i];
    __syncthreads();
    if (tid < 160) {
      const int j = tid;
      float a = 0.f;
#pragma unroll 8
      for (int d = 0; d < D_DIM; d++) a += rk_s[d] * aw1[d * 160 + j];
      h1[k * 160 + j] = fmaxf(a, 0.f);
    }
    return;
  }

  if (blk < ABLKS + QBLKS) {
    int row = (blk - ABLKS) * 4 + (tid >> 6);
    int lane = tid & 63;
    if (lane == 0) rowmax[row] = 0u;
    unsigned char* dst = qb + (long)row * D_DIM;
    if (row >= M_REAL) {
#pragma unroll
      for (int i = 0; i < 10; i++) dst[i * 64 + lane] = 0;
      return;
    }
    const float* src = q + (long)row * D_DIM;
    float v[10];
    float ss = 0.f;
#pragma unroll
    for (int i = 0; i < 10; i++) { v[i] = src[i * 64 + lane]; ss += v[i] * v[i]; }
#pragma unroll
    for (int off = 32; off > 0; off >>= 1) ss += __shfl_xor(ss, off);
    float inv = 1.f / (sqrtf(ss) + 1e-6f);
    if (lane == 0) qinv[row] = inv * (1.f / 16.f);  // fold r-scale
#pragma unroll
    for (int i = 0; i < 10; i++) dst[i * 64 + lane] = f2fp8(v[i]);
    return;
  }

  {
    int row = (blk - ABLKS - QBLKS) * 4 + (tid >> 6);
    int lane = tid & 63;
    unsigned char* dst = rb + (long)row * D_DIM;
    if (row >= N_REAL) {
#pragma unroll
      for (int i = 0; i < 10; i++) dst[i * 64 + lane] = 0;
      return;
    }
    const float* src = r + (long)row * D_DIM;
    float v[10];
    float ss = 0.f;
#pragma unroll
    for (int i = 0; i < 10; i++) { v[i] = src[i * 64 + lane]; ss += v[i] * v[i]; }
#pragma unroll
    for (int off = 32; off > 0; off >>= 1) ss += __shfl_xor(ss, off);
    float sc = 16.f / (sqrtf(ss) + 1e-6f);   // normalize, x16 into e4m3 normals
#pragma unroll
    for (int i = 0; i < 10; i++) dst[i * 64 + lane] = f2fp8(v[i] * sc);
  }
}

// =====================================================================
// Kernel B: fused fp8 MFMA GEMM + row-max.
//   BK=64 as two BK=32 halves; tile row = 32 B; frag = 8 B (ds_read_b64).
//   Each thread stages one 16-B chunk per operand-half (4 gl_lds16/iter).
//   XCD-ownership swizzle, bm fastest (Q-subset + R-tile L2-resident).
// =====================================================================
__global__ __launch_bounds__(256) void sim_max_kernel(
    const unsigned char* __restrict__ Qb,
    const unsigned char* __restrict__ Rb,
    unsigned* __restrict__ rowmax) {
  __shared__ __attribute__((aligned(16))) unsigned char As[2][BM * 32];  // 2x4 KB
  __shared__ __attribute__((aligned(16))) unsigned char Bs[2][BN * 32];  // 2x4 KB

  const int xcd = blockIdx.x & 7;
  const int idx = blockIdx.x >> 3;
  const int bm = xcd + 8 * (idx % MCHUNK);
  const int bn = idx / MCHUNK;
  if (bm >= MTILES) return;

  const int tid = threadIdx.x;
  const int wave = tid >> 6, lane = tid & 63;
  const int wr = wave >> 1, wc = wave & 1;
  const int q = lane >> 4, m0 = lane & 15;

  // staging geometry: thread stages 16-B chunk at LDS byte f = tid*16
  const int f = tid * 16;
  const int rowS = f >> 5;       // row stride 32 B (32 fp8 k-bytes)
  const int colS = f & 31;       // 0 or 16

  const int aBase = bm * BM;
  const int bBase = bn * BN;

  f32x4 zero = {0.f, 0.f, 0.f, 0.f};
  f32x4 acc[4][4];
#pragma unroll
  for (int i = 0; i < 4; i++)
#pragma unroll
    for (int j = 0; j < 4; j++) acc[i][j] = zero;

  for (int k0 = 0; k0 < D_DIM; k0 += 64) {
#pragma unroll
    for (int h = 0; h < 2; h++) {
      gl_lds16(Qb + (size_t)(aBase + rowS) * D_DIM + k0 + h * 32 + colS, &As[h][f]);
      gl_lds16(Rb + (size_t)(bBase + rowS) * D_DIM + k0 + h * 32 + colS, &Bs[h][f]);
    }
    __syncthreads();  // drains vmcnt -> both LDS sub-tiles ready

#pragma unroll
    for (int h = 0; h < 2; h++) {
      long af[4], bfr[4];
#pragma unroll
      for (int mi = 0; mi < 4; mi++)
        af[mi] = *(const long*)&As[h][(wr * 64 + mi * 16 + m0) * 32 + q * 8];
#pragma unroll
      for (int ni = 0; ni < 4; ni++)
        bfr[ni] = *(const long*)&Bs[h][(wc * 64 + ni * 16 + m0) * 32 + q * 8];
#pragma unroll
      for (int mi = 0; mi < 4; mi++)
#pragma unroll
        for (int ni = 0; ni < 4; ni++)
          acc[mi][ni] = __builtin_amdgcn_mfma_f32_16x16x32_fp8_fp8(
              af[mi], bfr[ni], acc[mi][ni], 0, 0, 0);
    }
    __syncthreads();  // protect LDS before next-iter overwrite
  }

  // epilogue: per-row max over this block's 128 columns, then global atomicMax
  const int colBase = bn * BN + wc * 64;
#pragma unroll
  for (int mi = 0; mi < 4; mi++) {
    float rmax[4] = {-3.0e38f, -3.0e38f, -3.0e38f, -3.0e38f};
#pragma unroll
    for (int ni = 0; ni < 4; ni++) {
      bool valid = (colBase + ni * 16 + m0) < N_REAL;
#pragma unroll
      for (int r = 0; r < 4; r++) {
        float v = valid ? acc[mi][ni][r] : -3.0e38f;
        rmax[r] = fmaxf(rmax[r], v);
      }
    }
#pragma unroll
    for (int r = 0; r < 4; r++) {
      float v = rmax[r];
      v = fmaxf(v, __shfl_xor(v, 1));
      v = fmaxf(v, __shfl_xor(v, 2));
      v = fmaxf(v, __shfl_xor(v, 4));
      v = fmaxf(v, __shfl_xor(v, 8));
      rmax[r] = v;
    }
    if (m0 == 0) {
      int row = bm * BM + wr * 64 + mi * 16 + q * 4;
#pragma unroll
      for (int r = 0; r < 4; r++)
        atomicMax(&rowmax[row + r], f2key(rmax[r]));
    }
  }
}

// =====================================================================
// Kernel T1: tail part 1 (unchanged from round 6).
// =====================================================================
__global__ __launch_bounds__(256) void tail1_kernel(
    const float* __restrict__ h1, const float* __restrict__ aw2,
    const unsigned* __restrict__ rowmax, const float* __restrict__ qinv,
    const float* __restrict__ hw1, const float* __restrict__ hb1,
    const float* __restrict__ hg2, const float* __restrict__ hbe2,
    float* __restrict__ favg, float* __restrict__ h1m,
    float* __restrict__ amean) {
  __shared__ __attribute__((aligned(16))) float S[12800];  // 51.2 KB
  const int blk = blockIdx.x;
  const int tid = threadIdx.x;
  const int wave = tid >> 6, lane = tid & 63;

  if (blk < 10) {
    const int d0 = blk * 64;
#pragma unroll
    for (int i = 0; i < 10; i++) S[i * 256 + tid] = h1[i * 256 + tid];
#pragma unroll
    for (int c = 0; c < 10; c++) {
      int e = c * 256 + tid;
      int row = e >> 4, col16 = e & 15;
      gl_lds16((const char*)aw2 + (size_t)row * D_DIM * 4 + d0 * 4 + col16 * 16,
               (char*)&S[2560] + e * 16);
    }
    __syncthreads();

    const int d = tid & 63, kg = tid >> 6;
    float a0 = 0.f, a1 = 0.f, a2 = 0.f, a3 = 0.f;
#pragma unroll 8
    for (int j = 0; j < 160; j++) {
      float w = S[2560 + j * 64 + d];
      a0 += S[(kg * 4 + 0) * 160 + j] * w;
      a1 += S[(kg * 4 + 1) * 160 + j] * w;
      a2 += S[(kg * 4 + 2) * 160 + j] * w;
      a3 += S[(kg * 4 + 3) * 160 + j] * w;
    }
    float p = fmaxf(a0, 0.f) + fmaxf(a1, 0.f) + fmaxf(a2, 0.f) + fmaxf(a3, 0.f);
    __syncthreads();
    S[kg * 64 + d] = p;
    __syncthreads();
    if (kg == 0)
      favg[d0 + d] = (S[d] + S[64 + d] + S[128 + d] + S[192 + d]) * (1.f / 16.f);
    return;
  }

  const int bO = (blk - 10) * 8;
  for (int e = tid; e < 8 * P_DIM; e += 256) {
    int row = bO * P_DIM + e;
    float mx = key2f(rowmax[row]);
    S[e] = 0.5f * (1.f - mx * qinv[row]);
  }
  __syncthreads();

#pragma unroll
  for (int i = 0; i < 2; i++) {
    int b = wave * 2 + i;
    float s = S[b * P_DIM + lane];
    s += S[b * P_DIM + lane + 64];
    s += S[b * P_DIM + lane + 128];
    if (lane < 33) s += S[b * P_DIM + lane + 192];
#pragma unroll
    for (int off = 32; off > 0; off >>= 1) s += __shfl_xor(s, off);
    if (lane == 0) amean[bO + b] = s * (1.f / 225.f);
  }

  const int j = tid & 127, bh = tid >> 7;
  float acc[4];
#pragma unroll
  for (int bb = 0; bb < 4; bb++) acc[bb] = hb1[j];

  for (int t = 0; t < 7; t++) {
    int p0 = t * 32;
#pragma unroll
    for (int c = 0; c < 4; c++) {
      int e = c * 256 + tid;
      int row = e >> 5, col16 = e & 31;
      gl_lds16((const char*)hw1 + (size_t)(p0 + row) * 128 * 4 + col16 * 16,
               (char*)&S[1800] + e * 16);
    }
    __syncthreads();
#pragma unroll 4
    for (int pr = 0; pr < 32; pr++) {
      float w = S[1800 + pr * 128 + j];
#pragma unroll
      for (int bb = 0; bb < 4; bb++)
        acc[bb] += S[(bh * 4 + bb) * P_DIM + p0 + pr] * w;
    }
    __syncthreads();
  }
  {
    float w = hw1[224 * 128 + j];
#pragma unroll
    for (int bb = 0; bb < 4; bb++)
      acc[bb] += S[(bh * 4 + bb) * P_DIM + 224] * w;
  }
#pragma unroll
  for (int bb = 0; bb < 4; bb++) {
    float h = fmaxf(acc[bb], 0.f) * hg2[j] + hbe2[j];
    h1m[(bO + bh * 4 + bb) * 128 + j] = h;
  }
}

// =====================================================================
// Kernel T2: tail part 2 (unchanged from round 6).
// =====================================================================
__global__ __launch_bounds__(256) void tail2_kernel(
    const float* __restrict__ q_img, const float* __restrict__ favg,
    const float* __restrict__ h1m, const float* __restrict__ amean,
    const float* __restrict__ hw2, const float* __restrict__ hb2,
    const float* __restrict__ hg3, const float* __restrict__ hbe3,
    const float* __restrict__ hw3, const float* __restrict__ hb3,
    const float* __restrict__ rw1, const float* __restrict__ rb1,
    const float* __restrict__ rg2, const float* __restrict__ rbe2,
    const float* __restrict__ rw2, const float* __restrict__ rb2,
    const float* __restrict__ rg3, const float* __restrict__ rbe3,
    const float* __restrict__ rw3, const float* __restrict__ rb3,
    float* __restrict__ out) {
  __shared__ __attribute__((aligned(16))) float S[14336];  // 57.3 KB
  const int tid = threadIdx.x;
  const int wave = tid >> 6, lane = tid & 63;
  const int bO = blockIdx.x * 8;

#pragma unroll
  for (int i = 0; i < 20; i++) {
    int e = i * 256 + tid;
    int d = e % D_DIM;
    S[e] = q_img[bO * D_DIM + e] - favg[d];
  }

#pragma unroll
  for (int c = 0; c < 4; c++) {
    int e = c * 256 + tid;
    int row = e >> 5, col16 = e & 31;
    gl_lds16((const char*)rw1 + (size_t)row * 128 * 4 + col16 * 16,
             (char*)&S[5120] + e * 16);
  }
  __syncthreads();

  const int j = tid & 127, bh = tid >> 7;
  float acc[4];
#pragma unroll
  for (int bb = 0; bb < 4; bb++) acc[bb] = rb1[j];

  for (int t = 0; t < 20; t++) {
    int bufC = 5120 + (t & 1) * 4096;
    int bufN = 5120 + ((t + 1) & 1) * 4096;
    if (t < 19) {
      int d0n = (t + 1) * 32;
#pragma unroll
      for (int c = 0; c < 4; c++) {
        int e = c * 256 + tid;
        int row = e >> 5, col16 = e & 31;
        gl_lds16((const char*)rw1 + (size_t)(d0n + row) * 128 * 4 + col16 * 16,
                 (char*)&S[bufN] + e * 16);
      }
    }
    int d0 = t * 32;
#pragma unroll 4
    for (int dr = 0; dr < 32; dr++) {
      float w = S[bufC + dr * 128 + j];
#pragma unroll
      for (int bb = 0; bb < 4; bb++)
        acc[bb] += S[(bh * 4 + bb) * D_DIM + d0 + dr] * w;
    }
    __syncthreads();
  }

#pragma unroll
  for (int bb = 0; bb < 4; bb++) {
    float h = fmaxf(acc[bb], 0.f) * rg2[j] + rbe2[j];
    S[13312 + (bh * 4 + bb) * 128 + j] = h;
  }
  __syncthreads();

#pragma unroll
  for (int c = 0; c < 8; c++) {
    int e = c * 256 + tid;
    gl_lds16((const char*)rw2 + e * 16, (char*)&S[0] + e * 16);
  }
#pragma unroll
  for (int i = 0; i < 4; i++) {
    int e = i * 256 + tid;
    S[8192 + e] = h1m[bO * 128 + e];
  }
  __syncthreads();

  {
    const int n = tid & 63, bg = tid >> 6;
#pragma unroll
    for (int bb = 0; bb < 2; bb++) {
      int b = bg * 2 + bb;
      float a = rb2[n];
#pragma unroll 8
      for (int jj = 0; jj < 128; jj++) a += S[13312 + b * 128 + jj] * S[jj * 64 + n];
      S[10240 + b * 64 + n] = fmaxf(a, 0.f) * rg3[n] + rbe3[n];
    }
  }
  __syncthreads();

#pragma unroll
  for (int c = 0; c < 8; c++) {
    int e = c * 256 + tid;
    gl_lds16((const char*)hw2 + e * 16, (char*)&S[0] + e * 16);
  }

#pragma unroll
  for (int i = 0; i < 2; i++) {
    int b = wave * 2 + i;
    float v = S[10240 + b * 64 + lane] * rw3[lane];
#pragma unroll
    for (int off = 32; off > 0; off >>= 1) v += __shfl_xor(v, off);
    if (lane == 0) S[11264 + b] = sigmoidf(v + rb3[0]);
  }
  __syncthreads();

  {
    const int n = tid & 63, bg = tid >> 6;
#pragma unroll
    for (int bb = 0; bb < 2; bb++) {
      int b = bg * 2 + bb;
      float a = hb2[n];
#pragma unroll 8
      for (int jj = 0; jj < 128; jj++) a += S[8192 + b * 128 + jj] * S[jj * 64 + n];
      S[10752 + b * 64 + n] = fmaxf(a, 0.f) * hg3[n] + hbe3[n];
    }
  }
  __syncthreads();

#pragma unroll
  for (int i = 0; i < 2; i++) {
    int b = wave * 2 + i;
    float v = S[10752 + b * 64 + lane] * hw3[lane];
#pragma unroll
    for (int off = 32; off > 0; off >>= 1) v += __shfl_xor(v, off);
    if (lane == 0) S[11272 + b] = sigmoidf(v + hb3[0]);
  }
  __syncthreads();

  if (tid < 8) {
    int b = bO + tid;
    out[b] = 0.5f * (S[11264 + tid] + S[11272 + tid]) + amean[b];
  }
}

// ---------------- launch ----------------
extern "C" void kernel_launch(void* const* d_in, const int* in_sizes, int n_in,
                              void* d_out, int out_size, void* d_ws, size_t ws_size,
                              hipStream_t stream) {
  const float* q_patch = (const float*)d_in[0];
  const float* r_patch = (const float*)d_in[1];
  const float* q_img   = (const float*)d_in[2];
  const float* r_img   = (const float*)d_in[3];
  const float* adpt_w1 = (const float*)d_in[4];
  const float* adpt_w2 = (const float*)d_in[5];
  const float* dh_w1 = (const float*)d_in[6];
  const float* dh_b1 = (const float*)d_in[7];
  const float* dh_g2 = (const float*)d_in[8];
  const float* dh_be2 = (const float*)d_in[9];
  const float* dh_w2 = (const float*)d_in[10];
  const float* dh_b2 = (const float*)d_in[11];
  const float* dh_g3 = (const float*)d_in[12];
  const float* dh_be3 = (const float*)d_in[13];
  const float* dh_w3 = (const float*)d_in[14];
  const float* dh_b3 = (const float*)d_in[15];
  const float* dr_w1 = (const float*)d_in[16];
  const float* dr_b1 = (const float*)d_in[17];
  const float* dr_g2 = (const float*)d_in[18];
  const float* dr_be2 = (const float*)d_in[19];
  const float* dr_w2 = (const float*)d_in[20];
  const float* dr_b2 = (const float*)d_in[21];
  const float* dr_g3 = (const float*)d_in[22];
  const float* dr_be3 = (const float*)d_in[23];
  const float* dr_w3 = (const float*)d_in[24];
  const float* dr_b3 = (const float*)d_in[25];

  // ws layout (bytes) — fp8 staging buffers
  const size_t QB_BYTES = (size_t)MPAD * D_DIM;   // 9,256,960
  const size_t RB_BYTES = (size_t)NPAD * D_DIM;   // 2,375,680
  char* ws = (char*)d_ws;
  unsigned char* qb = (unsigned char*)(ws);
  unsigned char* rb = (unsigned char*)(ws + QB_BYTES);
  float* qinv        = (float*)(ws + QB_BYTES + RB_BYTES);
  unsigned* rowmax   = (unsigned*)(ws + QB_BYTES + RB_BYTES + (size_t)M_REAL * 4);
  float* h1          = (float*)(ws + QB_BYTES + RB_BYTES + (size_t)M_REAL * 4 + (size_t)MPAD * 4);
  float* favg        = h1 + 16 * 160;
  float* h1m         = favg + D_DIM;
  float* amean       = h1m + 64 * 128;

  stage_all_kernel<<<ABLKS + QBLKS + RBLKS, 256, 0, stream>>>(
      q_patch, r_patch, r_img, adpt_w1, qb, rb, qinv, rowmax, h1);
  sim_max_kernel<<<8 * MCHUNK * NTILES, 256, 0, stream>>>(qb, rb, rowmax);
  tail1_kernel<<<18, 256, 0, stream>>>(
      h1, adpt_w2, rowmax, qinv, dh_w1, dh_b1, dh_g2, dh_be2,
      favg, h1m, amean);
  tail2_kernel<<<8, 256, 0, stream>>>(
      q_img, favg, h1m, amean,
      dh_w2, dh_b2, dh_g3, dh_be3, dh_w3, dh_b3,
      dr_w1, dr_b1, dr_g2, dr_be2, dr_w2, dr_b2, dr_g3, dr_be3, dr_w3, dr_b3,
      (float*)d_out);
}

// Round 8
// 279.585 us; speedup vs baseline: 1.2495x; 1.0102x over previous
//
#include <hip/hip_runtime.h>
#include <stdint.h>

// ---------------- problem dims ----------------
#define B_DIM 64
#define P_DIM 225
#define K_DIM 16
#define D_DIM 640
#define M_REAL (B_DIM * P_DIM)   // 14400 query rows
#define N_REAL (K_DIM * P_DIM)   // 3600 reference rows

// ---------------- GEMM tiling ----------------
#define BM 128
#define BN 128
#define MTILES 113               // ceil(14400/128) -> Mpad 14464
#define NTILES 29                // ceil(3600/128)  -> Npad 3712
#define MPAD (MTILES * BM)
#define NPAD (NTILES * BN)
#define MCHUNK 15                // ceil(MTILES/8) per-XCD bm groups

typedef float f32x4 __attribute__((ext_vector_type(4)));

// ---------------- helpers ----------------
// float -> OCP e4m3 byte (v_cvt_pk_fp8_f32)
__device__ __forceinline__ unsigned char f2fp8(float f) {
  int r = __builtin_amdgcn_cvt_pk_fp8_f32(f, f, 0, false);
  return (unsigned char)(r & 0xFF);
}

// monotone float -> uint key (order-preserving), for atomicMax on floats
__device__ __forceinline__ unsigned f2key(float f) {
  union { float f; unsigned u; } v; v.f = f;
  unsigned u = v.u;
  return (u & 0x80000000u) ? ~u : (u | 0x80000000u);
}
__device__ __forceinline__ float key2f(unsigned k) {
  unsigned b = (k & 0x80000000u) ? (k ^ 0x80000000u) : ~k;
  union { unsigned u; float f; } v; v.u = b;
  return v.f;
}

__device__ __forceinline__ void gl_lds16(const void* g, void* l) {
  __builtin_amdgcn_global_load_lds(
      (const __attribute__((address_space(1))) void*)g,
      (__attribute__((address_space(3))) void*)l,
      16, 0, 0);
}

__device__ __forceinline__ float sigmoidf(float x) {
  return 1.f / (1.f + expf(-x));
}

// =====================================================================
// Kernel A: staging (fp8 e4m3 outputs) — unchanged from round 7
// =====================================================================
#define QBLKS (MPAD / 4)
#define RBLKS (NPAD / 4)
#define ABLKS 16
__global__ __launch_bounds__(256) void stage_all_kernel(
    const float* __restrict__ q, const float* __restrict__ r,
    const float* __restrict__ r_img, const float* __restrict__ aw1,
    unsigned char* __restrict__ qb, unsigned char* __restrict__ rb,
    float* __restrict__ qinv, unsigned* __restrict__ rowmax,
    float* __restrict__ h1) {
  const int blk = blockIdx.x;
  const int tid = threadIdx.x;

  if (blk < ABLKS) {
    __shared__ float rk_s[D_DIM];
    const int k = blk;
    for (int i = tid; i < D_DIM; i += 256) rk_s[i] = r_img[k * D_DIM + i];
    __syncthreads();
    if (tid < 160) {
      const int j = tid;
      float a = 0.f;
#pragma unroll 8
      for (int d = 0; d < D_DIM; d++) a += rk_s[d] * aw1[d * 160 + j];
      h1[k * 160 + j] = fmaxf(a, 0.f);
    }
    return;
  }

  if (blk < ABLKS + QBLKS) {
    int row = (blk - ABLKS) * 4 + (tid >> 6);
    int lane = tid & 63;
    if (lane == 0) rowmax[row] = 0u;
    unsigned char* dst = qb + (long)row * D_DIM;
    if (row >= M_REAL) {
#pragma unroll
      for (int i = 0; i < 10; i++) dst[i * 64 + lane] = 0;
      return;
    }
    const float* src = q + (long)row * D_DIM;
    float v[10];
    float ss = 0.f;
#pragma unroll
    for (int i = 0; i < 10; i++) { v[i] = src[i * 64 + lane]; ss += v[i] * v[i]; }
#pragma unroll
    for (int off = 32; off > 0; off >>= 1) ss += __shfl_xor(ss, off);
    float inv = 1.f / (sqrtf(ss) + 1e-6f);
    if (lane == 0) qinv[row] = inv * (1.f / 16.f);  // fold r-scale
#pragma unroll
    for (int i = 0; i < 10; i++) dst[i * 64 + lane] = f2fp8(v[i]);
    return;
  }

  {
    int row = (blk - ABLKS - QBLKS) * 4 + (tid >> 6);
    int lane = tid & 63;
    unsigned char* dst = rb + (long)row * D_DIM;
    if (row >= N_REAL) {
#pragma unroll
      for (int i = 0; i < 10; i++) dst[i * 64 + lane] = 0;
      return;
    }
    const float* src = r + (long)row * D_DIM;
    float v[10];
    float ss = 0.f;
#pragma unroll
    for (int i = 0; i < 10; i++) { v[i] = src[i * 64 + lane]; ss += v[i] * v[i]; }
#pragma unroll
    for (int off = 32; off > 0; off >>= 1) ss += __shfl_xor(ss, off);
    float sc = 16.f / (sqrtf(ss) + 1e-6f);   // normalize, x16 into e4m3 normals
#pragma unroll
    for (int i = 0; i < 10; i++) dst[i * 64 + lane] = f2fp8(v[i] * sc);
  }
}

// =====================================================================
// Kernel B: fused fp8 MFMA GEMM + row-max, chunk-planar LDS layout.
//   LDS tile = [8 groups][2 c][16 rows][16 B]: slot = g*32 + c*16 + rloc.
//   Frag read bank = (4*m0 + 2*h8) mod 32 -> all 32 banks, 2-way (free),
//   vs round-7 row-major's 16-banks/4-way. Staging permutes lanes only
//   (same global footprint, still base+lane*16 contiguous in LDS).
// =====================================================================
__global__ __launch_bounds__(256) void sim_max_kernel(
    const unsigned char* __restrict__ Qb,
    const unsigned char* __restrict__ Rb,
    unsigned* __restrict__ rowmax) {
  __shared__ __attribute__((aligned(16))) unsigned char As[2][BM * 32];  // 2x4 KB
  __shared__ __attribute__((aligned(16))) unsigned char Bs[2][BN * 32];  // 2x4 KB

  const int xcd = blockIdx.x & 7;
  const int idx = blockIdx.x >> 3;
  const int bm = xcd + 8 * (idx % MCHUNK);
  const int bn = idx / MCHUNK;
  if (bm >= MTILES) return;

  const int tid = threadIdx.x;
  const int wave = tid >> 6, lane = tid & 63;
  const int wr = wave >> 1, wc = wave & 1;
  const int q = lane >> 4, m0 = lane & 15;
  const int cq = q >> 1, h8 = q & 1;   // 16-B chunk + 8-B half of frag

  // ---- staging geometry (chunk-planar): thread stages slot s = tid ----
  //   slot s -> global (row rS, 16-B chunk cS):
  const int rS = ((tid >> 5) << 4) | (tid & 15);
  const int cS = (tid >> 4) & 1;
  const int f = tid * 16;              // LDS byte (contiguous, lane*16)

  // ---- frag read LDS byte offsets (within As[h]/Bs[h]) ----
  //   byte(g, c, rloc, h8) = (g*32 + c*16 + rloc)*16 + h8*8
  const int aG = wr * 4, bG = wc * 4;  // group base per wave
  const int fragBase = (cq * 16 + m0) * 16 + h8 * 8;

  const int aBase = bm * BM;
  const int bBase = bn * BN;

  f32x4 zero = {0.f, 0.f, 0.f, 0.f};
  f32x4 acc[4][4];
#pragma unroll
  for (int i = 0; i < 4; i++)
#pragma unroll
    for (int j = 0; j < 4; j++) acc[i][j] = zero;

  for (int k0 = 0; k0 < D_DIM; k0 += 64) {
#pragma unroll
    for (int h = 0; h < 2; h++) {
      gl_lds16(Qb + (size_t)(aBase + rS) * D_DIM + k0 + h * 32 + cS * 16, &As[h][f]);
      gl_lds16(Rb + (size_t)(bBase + rS) * D_DIM + k0 + h * 32 + cS * 16, &Bs[h][f]);
    }
    __syncthreads();  // drains vmcnt -> both LDS sub-tiles ready

#pragma unroll
    for (int h = 0; h < 2; h++) {
      long af[4], bfr[4];
#pragma unroll
      for (int mi = 0; mi < 4; mi++)
        af[mi] = *(const long*)&As[h][(aG + mi) * 512 + fragBase];
#pragma unroll
      for (int ni = 0; ni < 4; ni++)
        bfr[ni] = *(const long*)&Bs[h][(bG + ni) * 512 + fragBase];
#pragma unroll
      for (int mi = 0; mi < 4; mi++)
#pragma unroll
        for (int ni = 0; ni < 4; ni++)
          acc[mi][ni] = __builtin_amdgcn_mfma_f32_16x16x32_fp8_fp8(
              af[mi], bfr[ni], acc[mi][ni], 0, 0, 0);
    }
    __syncthreads();  // protect LDS before next-iter overwrite
  }

  // epilogue: per-row max over this block's 128 columns, then global atomicMax
  const int colBase = bn * BN + wc * 64;
#pragma unroll
  for (int mi = 0; mi < 4; mi++) {
    float rmax[4] = {-3.0e38f, -3.0e38f, -3.0e38f, -3.0e38f};
#pragma unroll
    for (int ni = 0; ni < 4; ni++) {
      bool valid = (colBase + ni * 16 + m0) < N_REAL;
#pragma unroll
      for (int r = 0; r < 4; r++) {
        float v = valid ? acc[mi][ni][r] : -3.0e38f;
        rmax[r] = fmaxf(rmax[r], v);
      }
    }
#pragma unroll
    for (int r = 0; r < 4; r++) {
      float v = rmax[r];
      v = fmaxf(v, __shfl_xor(v, 1));
      v = fmaxf(v, __shfl_xor(v, 2));
      v = fmaxf(v, __shfl_xor(v, 4));
      v = fmaxf(v, __shfl_xor(v, 8));
      rmax[r] = v;
    }
    if (m0 == 0) {
      int row = bm * BM + wr * 64 + mi * 16 + q * 4;
#pragma unroll
      for (int r = 0; r < 4; r++)
        atomicMax(&rowmax[row + r], f2key(rmax[r]));
    }
  }
}

// =====================================================================
// Kernel T1: tail part 1 (unchanged).
// =====================================================================
__global__ __launch_bounds__(256) void tail1_kernel(
    const float* __restrict__ h1, const float* __restrict__ aw2,
    const unsigned* __restrict__ rowmax, const float* __restrict__ qinv,
    const float* __restrict__ hw1, const float* __restrict__ hb1,
    const float* __restrict__ hg2, const float* __restrict__ hbe2,
    float* __restrict__ favg, float* __restrict__ h1m,
    float* __restrict__ amean) {
  __shared__ __attribute__((aligned(16))) float S[12800];  // 51.2 KB
  const int blk = blockIdx.x;
  const int tid = threadIdx.x;
  const int wave = tid >> 6, lane = tid & 63;

  if (blk < 10) {
    const int d0 = blk * 64;
#pragma unroll
    for (int i = 0; i < 10; i++) S[i * 256 + tid] = h1[i * 256 + tid];
#pragma unroll
    for (int c = 0; c < 10; c++) {
      int e = c * 256 + tid;
      int row = e >> 4, col16 = e & 15;
      gl_lds16((const char*)aw2 + (size_t)row * D_DIM * 4 + d0 * 4 + col16 * 16,
               (char*)&S[2560] + e * 16);
    }
    __syncthreads();

    const int d = tid & 63, kg = tid >> 6;
    float a0 = 0.f, a1 = 0.f, a2 = 0.f, a3 = 0.f;
#pragma unroll 8
    for (int j = 0; j < 160; j++) {
      float w = S[2560 + j * 64 + d];
      a0 += S[(kg * 4 + 0) * 160 + j] * w;
      a1 += S[(kg * 4 + 1) * 160 + j] * w;
      a2 += S[(kg * 4 + 2) * 160 + j] * w;
      a3 += S[(kg * 4 + 3) * 160 + j] * w;
    }
    float p = fmaxf(a0, 0.f) + fmaxf(a1, 0.f) + fmaxf(a2, 0.f) + fmaxf(a3, 0.f);
    __syncthreads();
    S[kg * 64 + d] = p;
    __syncthreads();
    if (kg == 0)
      favg[d0 + d] = (S[d] + S[64 + d] + S[128 + d] + S[192 + d]) * (1.f / 16.f);
    return;
  }

  const int bO = (blk - 10) * 8;
  for (int e = tid; e < 8 * P_DIM; e += 256) {
    int row = bO * P_DIM + e;
    float mx = key2f(rowmax[row]);
    S[e] = 0.5f * (1.f - mx * qinv[row]);
  }
  __syncthreads();

#pragma unroll
  for (int i = 0; i < 2; i++) {
    int b = wave * 2 + i;
    float s = S[b * P_DIM + lane];
    s += S[b * P_DIM + lane + 64];
    s += S[b * P_DIM + lane + 128];
    if (lane < 33) s += S[b * P_DIM + lane + 192];
#pragma unroll
    for (int off = 32; off > 0; off >>= 1) s += __shfl_xor(s, off);
    if (lane == 0) amean[bO + b] = s * (1.f / 225.f);
  }

  const int j = tid & 127, bh = tid >> 7;
  float acc[4];
#pragma unroll
  for (int bb = 0; bb < 4; bb++) acc[bb] = hb1[j];

  for (int t = 0; t < 7; t++) {
    int p0 = t * 32;
#pragma unroll
    for (int c = 0; c < 4; c++) {
      int e = c * 256 + tid;
      int row = e >> 5, col16 = e & 31;
      gl_lds16((const char*)hw1 + (size_t)(p0 + row) * 128 * 4 + col16 * 16,
               (char*)&S[1800] + e * 16);
    }
    __syncthreads();
#pragma unroll 4
    for (int pr = 0; pr < 32; pr++) {
      float w = S[1800 + pr * 128 + j];
#pragma unroll
      for (int bb = 0; bb < 4; bb++)
        acc[bb] += S[(bh * 4 + bb) * P_DIM + p0 + pr] * w;
    }
    __syncthreads();
  }
  {
    float w = hw1[224 * 128 + j];
#pragma unroll
    for (int bb = 0; bb < 4; bb++)
      acc[bb] += S[(bh * 4 + bb) * P_DIM + 224] * w;
  }
#pragma unroll
  for (int bb = 0; bb < 4; bb++) {
    float h = fmaxf(acc[bb], 0.f) * hg2[j] + hbe2[j];
    h1m[(bO + bh * 4 + bb) * 128 + j] = h;
  }
}

// =====================================================================
// Kernel T2: tail part 2 (unchanged).
// =====================================================================
__global__ __launch_bounds__(256) void tail2_kernel(
    const float* __restrict__ q_img, const float* __restrict__ favg,
    const float* __restrict__ h1m, const float* __restrict__ amean,
    const float* __restrict__ hw2, const float* __restrict__ hb2,
    const float* __restrict__ hg3, const float* __restrict__ hbe3,
    const float* __restrict__ hw3, const float* __restrict__ hb3,
    const float* __restrict__ rw1, const float* __restrict__ rb1,
    const float* __restrict__ rg2, const float* __restrict__ rbe2,
    const float* __restrict__ rw2, const float* __restrict__ rb2,
    const float* __restrict__ rg3, const float* __restrict__ rbe3,
    const float* __restrict__ rw3, const float* __restrict__ rb3,
    float* __restrict__ out) {
  __shared__ __attribute__((aligned(16))) float S[14336];  // 57.3 KB
  const int tid = threadIdx.x;
  const int wave = tid >> 6, lane = tid & 63;
  const int bO = blockIdx.x * 8;

#pragma unroll
  for (int i = 0; i < 20; i++) {
    int e = i * 256 + tid;
    int d = e % D_DIM;
    S[e] = q_img[bO * D_DIM + e] - favg[d];
  }

#pragma unroll
  for (int c = 0; c < 4; c++) {
    int e = c * 256 + tid;
    int row = e >> 5, col16 = e & 31;
    gl_lds16((const char*)rw1 + (size_t)row * 128 * 4 + col16 * 16,
             (char*)&S[5120] + e * 16);
  }
  __syncthreads();

  const int j = tid & 127, bh = tid >> 7;
  float acc[4];
#pragma unroll
  for (int bb = 0; bb < 4; bb++) acc[bb] = rb1[j];

  for (int t = 0; t < 20; t++) {
    int bufC = 5120 + (t & 1) * 4096;
    int bufN = 5120 + ((t + 1) & 1) * 4096;
    if (t < 19) {
      int d0n = (t + 1) * 32;
#pragma unroll
      for (int c = 0; c < 4; c++) {
        int e = c * 256 + tid;
        int row = e >> 5, col16 = e & 31;
        gl_lds16((const char*)rw1 + (size_t)(d0n + row) * 128 * 4 + col16 * 16,
                 (char*)&S[bufN] + e * 16);
      }
    }
    int d0 = t * 32;
#pragma unroll 4
    for (int dr = 0; dr < 32; dr++) {
      float w = S[bufC + dr * 128 + j];
#pragma unroll
      for (int bb = 0; bb < 4; bb++)
        acc[bb] += S[(bh * 4 + bb) * D_DIM + d0 + dr] * w;
    }
    __syncthreads();
  }

#pragma unroll
  for (int bb = 0; bb < 4; bb++) {
    float h = fmaxf(acc[bb], 0.f) * rg2[j] + rbe2[j];
    S[13312 + (bh * 4 + bb) * 128 + j] = h;
  }
  __syncthreads();

#pragma unroll
  for (int c = 0; c < 8; c++) {
    int e = c * 256 + tid;
    gl_lds16((const char*)rw2 + e * 16, (char*)&S[0] + e * 16);
  }
#pragma unroll
  for (int i = 0; i < 4; i++) {
    int e = i * 256 + tid;
    S[8192 + e] = h1m[bO * 128 + e];
  }
  __syncthreads();

  {
    const int n = tid & 63, bg = tid >> 6;
#pragma unroll
    for (int bb = 0; bb < 2; bb++) {
      int b = bg * 2 + bb;
      float a = rb2[n];
#pragma unroll 8
      for (int jj = 0; jj < 128; jj++) a += S[13312 + b * 128 + jj] * S[jj * 64 + n];
      S[10240 + b * 64 + n] = fmaxf(a, 0.f) * rg3[n] + rbe3[n];
    }
  }
  __syncthreads();

#pragma unroll
  for (int c = 0; c < 8; c++) {
    int e = c * 256 + tid;
    gl_lds16((const char*)hw2 + e * 16, (char*)&S[0] + e * 16);
  }

#pragma unroll
  for (int i = 0; i < 2; i++) {
    int b = wave * 2 + i;
    float v = S[10240 + b * 64 + lane] * rw3[lane];
#pragma unroll
    for (int off = 32; off > 0; off >>= 1) v += __shfl_xor(v, off);
    if (lane == 0) S[11264 + b] = sigmoidf(v + rb3[0]);
  }
  __syncthreads();

  {
    const int n = tid & 63, bg = tid >> 6;
#pragma unroll
    for (int bb = 0; bb < 2; bb++) {
      int b = bg * 2 + bb;
      float a = hb2[n];
#pragma unroll 8
      for (int jj = 0; jj < 128; jj++) a += S[8192 + b * 128 + jj] * S[jj * 64 + n];
      S[10752 + b * 64 + n] = fmaxf(a, 0.f) * hg3[n] + hbe3[n];
    }
  }
  __syncthreads();

#pragma unroll
  for (int i = 0; i < 2; i++) {
    int b = wave * 2 + i;
    float v = S[10752 + b * 64 + lane] * hw3[lane];
#pragma unroll
    for (int off = 32; off > 0; off >>= 1) v += __shfl_xor(v, off);
    if (lane == 0) S[11272 + b] = sigmoidf(v + hb3[0]);
  }
  __syncthreads();

  if (tid < 8) {
    int b = bO + tid;
    out[b] = 0.5f * (S[11264 + tid] + S[11272 + tid]) + amean[b];
  }
}

// ---------------- launch ----------------
extern "C" void kernel_launch(void* const* d_in, const int* in_sizes, int n_in,
                              void* d_out, int out_size, void* d_ws, size_t ws_size,
                              hipStream_t stream) {
  const float* q_patch = (const float*)d_in[0];
  const float* r_patch = (const float*)d_in[1];
  const float* q_img   = (const float*)d_in[2];
  const float* r_img   = (const float*)d_in[3];
  const float* adpt_w1 = (const float*)d_in[4];
  const float* adpt_w2 = (const float*)d_in[5];
  const float* dh_w1 = (const float*)d_in[6];
  const float* dh_b1 = (const float*)d_in[7];
  const float* dh_g2 = (const float*)d_in[8];
  const float* dh_be2 = (const float*)d_in[9];
  const float* dh_w2 = (const float*)d_in[10];
  const float* dh_b2 = (const float*)d_in[11];
  const float* dh_g3 = (const float*)d_in[12];
  const float* dh_be3 = (const float*)d_in[13];
  const float* dh_w3 = (const float*)d_in[14];
  const float* dh_b3 = (const float*)d_in[15];
  const float* dr_w1 = (const float*)d_in[16];
  const float* dr_b1 = (const float*)d_in[17];
  const float* dr_g2 = (const float*)d_in[18];
  const float* dr_be2 = (const float*)d_in[19];
  const float* dr_w2 = (const float*)d_in[20];
  const float* dr_b2 = (const float*)d_in[21];
  const float* dr_g3 = (const float*)d_in[22];
  const float* dr_be3 = (const float*)d_in[23];
  const float* dr_w3 = (const float*)d_in[24];
  const float* dr_b3 = (const float*)d_in[25];

  // ws layout (bytes) — fp8 staging buffers
  const size_t QB_BYTES = (size_t)MPAD * D_DIM;   // 9,256,960
  const size_t RB_BYTES = (size_t)NPAD * D_DIM;   // 2,375,680
  char* ws = (char*)d_ws;
  unsigned char* qb = (unsigned char*)(ws);
  unsigned char* rb = (unsigned char*)(ws + QB_BYTES);
  float* qinv        = (float*)(ws + QB_BYTES + RB_BYTES);
  unsigned* rowmax   = (unsigned*)(ws + QB_BYTES + RB_BYTES + (size_t)M_REAL * 4);
  float* h1          = (float*)(ws + QB_BYTES + RB_BYTES + (size_t)M_REAL * 4 + (size_t)MPAD * 4);
  float* favg        = h1 + 16 * 160;
  float* h1m         = favg + D_DIM;
  float* amean       = h1m + 64 * 128;

  stage_all_kernel<<<ABLKS + QBLKS + RBLKS, 256, 0, stream>>>(
      q_patch, r_patch, r_img, adpt_w1, qb, rb, qinv, rowmax, h1);
  sim_max_kernel<<<8 * MCHUNK * NTILES, 256, 0, stream>>>(qb, rb, rowmax);
  tail1_kernel<<<18, 256, 0, stream>>>(
      h1, adpt_w2, rowmax, qinv, dh_w1, dh_b1, dh_g2, dh_be2,
      favg, h1m, amean);
  tail2_kernel<<<8, 256, 0, stream>>>(
      q_img, favg, h1m, amean,
      dh_w2, dh_b2, dh_g3, dh_be3, dh_w3, dh_b3,
      dr_w1, dr_b1, dr_g2, dr_be2, dr_w2, dr_b2, dr_g3, dr_be3, dr_w3, dr_b3,
      (float*)d_out);
}